// Round 1
// 293.244 us; speedup vs baseline: 1.0670x; 1.0670x over previous
//
#include <hip/hip_runtime.h>

#define N_NODES 100000
#define N_EDGES 1600000
#define F_IN    128
#define HID     64
#define N_CLASS 40
#define NEG_SLOPE 0.2f
#define ET (N_EDGES + N_NODES)          // 1,700,000
#define ROW_BLOCKS ((N_NODES + 63) / 64)

// ---- 2-level radix partition geometry ----
#define NCB   7
#define CAP1  294912
#define BPC   144
#define NFB   782
#define CAPF  2624
#define NT1   ((ET + 2047) / 2048)

typedef __attribute__((ext_vector_type(8))) short bf16x8;
typedef __attribute__((ext_vector_type(4))) float f32x4;

__device__ __forceinline__ unsigned int f2bf(float f) {  // fp32 -> bf16 (RNE)
    unsigned int u = __float_as_uint(f);
    return (u + 0x7fffu + ((u >> 16) & 1u)) >> 16;
}

// ---------------------------------------------------------------------------
// Weight prep (bf16, transposed [n][k]) + zero-init of all counter arrays.
// Grid-strided over 32 blocks (was 1 block -> serial bubble).
// ---------------------------------------------------------------------------
__global__ __launch_bounds__(256) void k_prepw(const float* __restrict__ W1,
        const float* __restrict__ Wc0, const float* __restrict__ Wc1,
        const float* __restrict__ W2,
        unsigned short* __restrict__ Wt1, unsigned short* __restrict__ Wtc0,
        unsigned short* __restrict__ Wtc1, unsigned short* __restrict__ W2t,
        int* __restrict__ zbuf, int zcount) {
    int g = blockIdx.x * 256 + threadIdx.x;
    int stride = gridDim.x * 256;
    for (int i = g; i < zcount; i += stride) zbuf[i] = 0;
    for (int i = g; i < F_IN * HID; i += stride) {
        int k = i >> 6, n = i & 63;
        Wt1[n * F_IN + k] = (unsigned short)f2bf(W1[i]);
    }
    for (int i = g; i < HID * HID; i += stride) {
        int k = i >> 6, n = i & 63;
        Wtc0[n * HID + k] = (unsigned short)f2bf(Wc0[i]);
        Wtc1[n * HID + k] = (unsigned short)f2bf(Wc1[i]);
    }
    for (int i = g; i < 48 * HID; i += stride) {
        int n = i >> 6, k = i & 63;
        W2t[n * HID + k] = (n < N_CLASS)
            ? (unsigned short)f2bf(W2[k * N_CLASS + n]) : (unsigned short)0;
    }
}

// ---------------------------------------------------------------------------
// FAT KERNEL: blocks [0, NT1) run partition level 1 (ballot-ranked, packed
// uint32 payload); blocks [NT1, NT1+ROW_BLOCKS) run the fused
// lin1 + GAT-0 gemm/att. The two are independent; fusing overlaps the
// memory/atomic-bound partition with the MFMA-bound GEMM in one launch.
// ---------------------------------------------------------------------------
__global__ __launch_bounds__(256) void k_p1lin(
        const int* __restrict__ ei, int* __restrict__ tail1,
        unsigned int* __restrict__ buf1,
        const float* __restrict__ x, const unsigned short* __restrict__ Wt1,
        const float* __restrict__ b1, const unsigned short* __restrict__ Wtc0,
        const float* __restrict__ att_s, const float* __restrict__ att_d,
        unsigned short* __restrict__ hb, float* __restrict__ as_,
        float* __restrict__ ad_) {
    __shared__ __align__(16) char smem[17408];   // union: eb[2048] u32 | xs 4x1088 f32
    __shared__ int hist[NCB], lb[NCB], cbase[NCB];
    int t = threadIdx.x;
    int lane = t & 63, w = t >> 6;

    if (blockIdx.x < NT1) {
        // ---------------- part1: edges -> 7 coarse buckets (dst>>14) -------
        unsigned int* eb = (unsigned int*)smem;
        int tileBase = blockIdx.x * 2048;
        int total = ET - tileBase; if (total > 2048) total = 2048;
        if (t < NCB) hist[t] = 0;
        __syncthreads();
        unsigned long long ltm = (1ull << lane) - 1ull;
        unsigned int pk[8]; int ps[8];
        #pragma unroll
        for (int r = 0; r < 8; ++r) {
            int i = tileBase + r * 256 + t;
            int s = 0, d = 0;
            bool valid = (i < ET);
            if (valid) {
                if (i < N_EDGES) { s = ei[i]; d = ei[N_EDGES + i]; }
                else             { s = d = i - N_EDGES; }
            }
            int b = valid ? (d >> 14) : -1;
            unsigned long long m[NCB];
            #pragma unroll
            for (int q = 0; q < NCB; ++q) m[q] = __ballot(b == q);
            int cnt = 0;
            #pragma unroll
            for (int q = 0; q < NCB; ++q) if (lane == q) cnt = __popcll(m[q]);
            int old = 0;
            if (lane < NCB) old = atomicAdd(&hist[lane], cnt);
            int bsafe = valid ? b : 0;
            int basew = __shfl(old, bsafe, 64);
            if (valid) {
                int rank = 0;
                #pragma unroll
                for (int q = 0; q < NCB; ++q)
                    if (b == q) rank = (int)__popcll(m[q] & ltm);
                pk[r] = ((unsigned int)s << 14) | ((unsigned int)d & 16383u);
                ps[r] = (basew + rank) | (b << 12);
            } else ps[r] = -1;
        }
        __syncthreads();
        if (t == 0) {
            int run = 0;
            #pragma unroll
            for (int q = 0; q < NCB; ++q) { int h = hist[q]; lb[q] = run; run += h; }
        }
        __syncthreads();
        if (t < NCB) {
            int g = (hist[t] > 0) ? atomicAdd(&tail1[t], hist[t]) : 0;
            cbase[t] = g - lb[t];
        }
        #pragma unroll
        for (int r = 0; r < 8; ++r) {
            if (ps[r] >= 0) {
                int b = ps[r] >> 12, pos = ps[r] & 4095;
                eb[lb[b] + pos] = pk[r];
            }
        }
        __syncthreads();
        int B1 = lb[1], B2 = lb[2], B3 = lb[3], B4 = lb[4], B5 = lb[5], B6 = lb[6];
        for (int j = t; j < total; j += 256) {
            unsigned int p = eb[j];
            int b = (j >= B1) + (j >= B2) + (j >= B3) + (j >= B4)
                  + (j >= B5) + (j >= B6);
            buf1[(size_t)b * CAP1 + cbase[b] + j] = p;
        }
    } else {
        // -------- fused lin1 + GAT-0 gemm/att (unchanged numerics) --------
        int quad = lane >> 4, lr = lane & 15;
        int rowg0 = (int)(blockIdx.x - NT1) * 64 + w * 16;
        float* xs = (float*)smem + w * (16 * 68);

        // GEMM 1: h0 = relu(x@W1+b1), K=128
        f32x4 zero = {0.f, 0.f, 0.f, 0.f};
        f32x4 acc[4] = {zero, zero, zero, zero};
        int arow = rowg0 + lr; if (arow >= N_NODES) arow = N_NODES - 1;
        const float* ab = x + (size_t)arow * F_IN;
        #pragma unroll
        for (int kc = 0; kc < 4; ++kc) {
            bf16x8 bw[4];
            #pragma unroll
            for (int nt = 0; nt < 4; ++nt)
                bw[nt] = *(const bf16x8*)(Wt1 + (nt * 16 + lr) * F_IN
                                          + kc * 32 + quad * 8);
            const float* ap = ab + kc * 32 + quad * 8;
            float4 a0 = *(const float4*)ap;
            float4 a1 = *(const float4*)(ap + 4);
            union { bf16x8 v; unsigned int u[4]; } af;
            af.u[0] = f2bf(a0.x) | (f2bf(a0.y) << 16);
            af.u[1] = f2bf(a0.z) | (f2bf(a0.w) << 16);
            af.u[2] = f2bf(a1.x) | (f2bf(a1.y) << 16);
            af.u[3] = f2bf(a1.z) | (f2bf(a1.w) << 16);
            #pragma unroll
            for (int nt = 0; nt < 4; ++nt)
                acc[nt] = __builtin_amdgcn_mfma_f32_16x16x32_bf16(
                              af.v, bw[nt], acc[nt], 0, 0, 0);
        }
        #pragma unroll
        for (int nt = 0; nt < 4; ++nt) {
            float bv = b1[nt * 16 + lr];
            #pragma unroll
            for (int reg = 0; reg < 4; ++reg)
                xs[(quad * 4 + reg) * 68 + nt * 16 + lr] =
                    fmaxf(acc[nt][reg] + bv, 0.f);
        }
        // GEMM 2: h = h0@Wc0, K=64, A from LDS (wave-local, no barriers)
        f32x4 acc2[4] = {zero, zero, zero, zero};
        #pragma unroll
        for (int kc = 0; kc < 2; ++kc) {
            bf16x8 bw[4];
            #pragma unroll
            for (int nt = 0; nt < 4; ++nt)
                bw[nt] = *(const bf16x8*)(Wtc0 + (nt * 16 + lr) * HID
                                          + kc * 32 + quad * 8);
            const float* ap = xs + lr * 68 + kc * 32 + quad * 8;
            float4 a0 = *(const float4*)ap;
            float4 a1 = *(const float4*)(ap + 4);
            union { bf16x8 v; unsigned int u[4]; } af;
            af.u[0] = f2bf(a0.x) | (f2bf(a0.y) << 16);
            af.u[1] = f2bf(a0.z) | (f2bf(a0.w) << 16);
            af.u[2] = f2bf(a1.x) | (f2bf(a1.y) << 16);
            af.u[3] = f2bf(a1.z) | (f2bf(a1.w) << 16);
            #pragma unroll
            for (int nt = 0; nt < 4; ++nt)
                acc2[nt] = __builtin_amdgcn_mfma_f32_16x16x32_bf16(
                              af.v, bw[nt], acc2[nt], 0, 0, 0);
        }
        float asv[4], adv[4];
        #pragma unroll
        for (int nt = 0; nt < 4; ++nt) {
            asv[nt] = att_s[nt * 16 + lr];
            adv[nt] = att_d[nt * 16 + lr];
        }
        #pragma unroll
        for (int reg = 0; reg < 4; ++reg) {
            float p1 = acc2[0][reg] * asv[0] + acc2[1][reg] * asv[1]
                     + acc2[2][reg] * asv[2] + acc2[3][reg] * asv[3];
            float p2 = acc2[0][reg] * adv[0] + acc2[1][reg] * adv[1]
                     + acc2[2][reg] * adv[2] + acc2[3][reg] * adv[3];
            #pragma unroll
            for (int off = 1; off < 16; off <<= 1) {
                p1 += __shfl_xor(p1, off, 64);
                p2 += __shfl_xor(p2, off, 64);
            }
            if (lr == 0) {
                int grow = rowg0 + quad * 4 + reg;
                if (grow < N_NODES) { as_[grow] = p1; ad_[grow] = p2; }
            }
        }
        #pragma unroll
        for (int nt = 0; nt < 4; ++nt)
            #pragma unroll
            for (int reg = 0; reg < 4; ++reg)
                xs[(quad * 4 + reg) * 68 + nt * 16 + lr] = acc2[nt][reg];
        #pragma unroll
        for (int j = 0; j < 2; ++j) {
            int task = j * 64 + lane;
            int r = task >> 3, g = task & 7;
            int grow = rowg0 + r;
            if (grow < N_NODES) {
                const float* p = xs + r * 68 + g * 8;
                uint4 u;
                u.x = f2bf(p[0]) | (f2bf(p[1]) << 16);
                u.y = f2bf(p[2]) | (f2bf(p[3]) << 16);
                u.z = f2bf(p[4]) | (f2bf(p[5]) << 16);
                u.w = f2bf(p[6]) | (f2bf(p[7]) << 16);
                *(uint4*)(hb + (size_t)grow * HID + g * 8) = u;
            }
        }
    }
}

// ---------------------------------------------------------------------------
// Partition level 2: coarse bucket -> 128 fine buckets. Packed uint payload.
// Last finishing block performs the fine-bucket exclusive scan (old k_fscan).
// ---------------------------------------------------------------------------
__global__ __launch_bounds__(256) void k_part2(const unsigned int* __restrict__ buf1,
        const int* __restrict__ tail1, int* __restrict__ fcnt,
        unsigned int* __restrict__ buf2, int* __restrict__ fbase,
        int* __restrict__ rowptr, int* __restrict__ done0) {
    __shared__ unsigned int eb[2048];
    __shared__ int hist[128], lbase[128], loff[128], goff[128], sc[128];
    __shared__ int lastflag, wsum4[4];
    int t = threadIdx.x;
    int cb   = blockIdx.x / BPC;
    int tile = blockIdx.x % BPC;
    int n1 = tail1[cb];
    int base = tile * 2048;
    if (base < n1) {
        int total = n1 - base; if (total > 2048) total = 2048;
        if (t < 128) hist[t] = 0;
        __syncthreads();
        unsigned int pr[8]; int fr[8];
        #pragma unroll
        for (int r = 0; r < 8; ++r) {
            int i = base + r * 256 + t;
            int f = -1; unsigned int p = 0;
            if (i < n1) {
                p = buf1[(size_t)cb * CAP1 + i];
                f = (int)((p >> 7) & 127u);
                atomicAdd(&hist[f], 1);
            }
            pr[r] = p; fr[r] = f;
        }
        __syncthreads();
        if (t < 128) sc[t] = hist[t];
        __syncthreads();
        for (int off = 1; off < 128; off <<= 1) {
            int u = (t < 128 && t >= off) ? sc[t - off] : 0;
            __syncthreads();
            if (t < 128) sc[t] += u;
            __syncthreads();
        }
        if (t < 128) { lbase[t] = sc[t] - hist[t]; loff[t] = 0; }
        __syncthreads();
        if (t < 128 && hist[t] > 0)
            goff[t] = atomicAdd(&fcnt[cb * 128 + t], hist[t]);
        #pragma unroll
        for (int r = 0; r < 8; ++r) {
            if (fr[r] >= 0) {
                int f = fr[r];
                int pos = lbase[f] + atomicAdd(&loff[f], 1);
                // payload: (s<<7)|dlow7, plus f in bits 24..30 for the flush
                eb[pos] = (pr[r] & 127u) | ((pr[r] >> 14) << 7)
                        | ((unsigned int)f << 24);
            }
        }
        __syncthreads();
        for (int j = t; j < total; j += 256) {
            unsigned int q = eb[j];
            int f = (int)(q >> 24);
            buf2[(size_t)(cb * 128 + f) * CAPF + goff[f] + (j - lbase[f])] =
                q & 0xFFFFFFu;
        }
    }
    // ---- done-ticket: last block of the grid runs the fine scan ----
    if (t == 0) lastflag = (atomicAdd(done0, 1) == NCB * BPC - 1);
    __syncthreads();
    if (lastflag) {
        __threadfence();                      // make fcnt atomics readable
        int k0 = t * 4;
        int v0 = (k0     < NFB) ? fcnt[k0]     : 0;
        int v1 = (k0 + 1 < NFB) ? fcnt[k0 + 1] : 0;
        int v2 = (k0 + 2 < NFB) ? fcnt[k0 + 2] : 0;
        int v3 = (k0 + 3 < NFB) ? fcnt[k0 + 3] : 0;
        int s1 = v0 + v1, s2 = s1 + v2, s3 = s2 + v3;
        int lane = t & 63, w = t >> 6;
        int ws = s3;
        #pragma unroll
        for (int off = 1; off < 64; off <<= 1) {
            int u = __shfl_up(ws, off, 64);
            if (lane >= off) ws += u;
        }
        if (lane == 63) wsum4[w] = ws;
        __syncthreads();
        int wb = 0;
        #pragma unroll
        for (int q = 0; q < 4; ++q) if (q < w) wb += wsum4[q];
        int ex = wb + ws - s3;                // exclusive base for this thread
        if (k0     < NFB) fbase[k0]     = ex;
        if (k0 + 1 < NFB) fbase[k0 + 1] = ex + v0;
        if (k0 + 2 < NFB) fbase[k0 + 2] = ex + s1;
        if (k0 + 3 < NFB) fbase[k0 + 3] = ex + s2;
        if (t == 0) rowptr[N_NODES] = ET;
    }
}

// ---------------------------------------------------------------------------
// Partition level 3: fine bucket -> exact per-node CSR + degree histogram.
// Last finishing block performs the 64-entry degree scan (old k_dscan).
// ---------------------------------------------------------------------------
__global__ __launch_bounds__(256) void k_part3(const unsigned int* __restrict__ buf2,
        const int* __restrict__ fcnt, const int* __restrict__ fbase,
        int* __restrict__ rowptr, int* __restrict__ col,
        int* __restrict__ dhistg, int* __restrict__ dbase,
        int* __restrict__ done1) {
    __shared__ unsigned int eb[CAPF];
    __shared__ int cs[CAPF];
    __shared__ int hist[128], lbase[128], loff[128], sc[128], dh[64];
    __shared__ int lastflag;
    int t = threadIdx.x;
    int fb = blockIdx.x;
    int nF = fcnt[fb];
    int gb = fbase[fb];
    int nbase = fb * 128;
    if (t < 128) hist[t] = 0;
    if (t >= 128 && t < 192) dh[t - 128] = 0;
    __syncthreads();
    for (int j = t; j < nF; j += 256) {
        unsigned int q = buf2[(size_t)fb * CAPF + j];
        eb[j] = q;
        atomicAdd(&hist[q & 127u], 1);
    }
    __syncthreads();
    if (t < 128) sc[t] = hist[t];
    __syncthreads();
    for (int off = 1; off < 128; off <<= 1) {
        int u = (t < 128 && t >= off) ? sc[t - off] : 0;
        __syncthreads();
        if (t < 128) sc[t] += u;
        __syncthreads();
    }
    if (t < 128) { lbase[t] = sc[t] - hist[t]; loff[t] = 0; }
    __syncthreads();
    if (t < 128 && nbase + t < N_NODES) {
        rowptr[nbase + t] = gb + lbase[t];
        int dg = hist[t]; if (dg > 63) dg = 63;
        atomicAdd(&dh[dg], 1);
    }
    for (int j = t; j < nF; j += 256) {
        unsigned int q = eb[j];
        int r = (int)(q & 127u);
        int p = lbase[r] + atomicAdd(&loff[r], 1);
        cs[p] = (int)(q >> 7);
    }
    __syncthreads();
    for (int j = t; j < nF; j += 256) col[gb + j] = cs[j];
    if (t < 64 && dh[t] > 0) atomicAdd(&dhistg[t], dh[t]);
    __syncthreads();
    // ---- done-ticket: last block runs the degree scan ----
    if (t == 0) lastflag = (atomicAdd(done1, 1) == NFB - 1);
    __syncthreads();
    if (lastflag && t < 64) {
        __threadfence();
        int v = dhistg[t];
        int s = v;
        #pragma unroll
        for (int off = 1; off < 64; off <<= 1) {
            int u = __shfl_up(s, off, 64);
            if (t >= off) s += u;
        }
        dbase[t] = s - v;   // exclusive
    }
}

// ---------------------------------------------------------------------------
__global__ __launch_bounds__(256) void k_dscatter(const int* __restrict__ rowptr,
        int* __restrict__ dbase, int* __restrict__ nodeord) {
    __shared__ int lh[64], goff[64];
    int t = threadIdx.x;
    if (t < 64) lh[t] = 0;
    __syncthreads();
    int i = blockIdx.x * 256 + t;
    int deg = -1, lrank = 0;
    if (i < N_NODES) {
        deg = rowptr[i + 1] - rowptr[i];
        if (deg > 63) deg = 63;
        lrank = atomicAdd(&lh[deg], 1);
    }
    __syncthreads();
    if (t < 64) goff[t] = (lh[t] > 0) ? atomicAdd(&dbase[t], lh[t]) : 0;
    __syncthreads();
    if (deg >= 0) nodeord[goff[deg] + lrank] = i;
}

// ---------------------------------------------------------------------------
// h = hin @ Wc (MFMA, bf16 in/out) ; as_/ad_ att dots. (layer 1)
// ---------------------------------------------------------------------------
__global__ __launch_bounds__(256) void k_gemm_att(
        const unsigned short* __restrict__ hin,
        const unsigned short* __restrict__ Wt,
        const float* __restrict__ att_s, const float* __restrict__ att_d,
        unsigned short* __restrict__ hb, float* __restrict__ as_,
        float* __restrict__ ad_) {
    __shared__ float xs[4][16 * 68];
    int t = threadIdx.x;
    int lane = t & 63, w = t >> 6;
    int quad = lane >> 4, lr = lane & 15;
    int rowg0 = blockIdx.x * 64 + w * 16;

    bf16x8 bfr[2][4];
    #pragma unroll
    for (int kc = 0; kc < 2; ++kc)
        #pragma unroll
        for (int nt = 0; nt < 4; ++nt)
            bfr[kc][nt] = *(const bf16x8*)(Wt + (nt * 16 + lr) * HID
                                           + kc * 32 + quad * 8);
    f32x4 zero = {0.f, 0.f, 0.f, 0.f};
    f32x4 acc[4] = {zero, zero, zero, zero};

    int arow = rowg0 + lr; if (arow >= N_NODES) arow = N_NODES - 1;
    #pragma unroll
    for (int kc = 0; kc < 2; ++kc) {
        bf16x8 af = *(const bf16x8*)(hin + (size_t)arow * HID
                                     + kc * 32 + quad * 8);
        #pragma unroll
        for (int nt = 0; nt < 4; ++nt)
            acc[nt] = __builtin_amdgcn_mfma_f32_16x16x32_bf16(
                          af, bfr[kc][nt], acc[nt], 0, 0, 0);
    }
    float asv[4], adv[4];
    #pragma unroll
    for (int nt = 0; nt < 4; ++nt) {
        asv[nt] = att_s[nt * 16 + lr];
        adv[nt] = att_d[nt * 16 + lr];
    }
    #pragma unroll
    for (int reg = 0; reg < 4; ++reg) {
        float p1 = acc[0][reg] * asv[0] + acc[1][reg] * asv[1]
                 + acc[2][reg] * asv[2] + acc[3][reg] * asv[3];
        float p2 = acc[0][reg] * adv[0] + acc[1][reg] * adv[1]
                 + acc[2][reg] * adv[2] + acc[3][reg] * adv[3];
        #pragma unroll
        for (int off = 1; off < 16; off <<= 1) {
            p1 += __shfl_xor(p1, off, 64);
            p2 += __shfl_xor(p2, off, 64);
        }
        if (lr == 0) {
            int grow = rowg0 + quad * 4 + reg;
            if (grow < N_NODES) { as_[grow] = p1; ad_[grow] = p2; }
        }
    }
    #pragma unroll
    for (int nt = 0; nt < 4; ++nt)
        #pragma unroll
        for (int reg = 0; reg < 4; ++reg)
            xs[w][(quad * 4 + reg) * 68 + nt * 16 + lr] = acc[nt][reg];
    #pragma unroll
    for (int j = 0; j < 2; ++j) {
        int task = j * 64 + lane;
        int r = task >> 3, g = task & 7;
        int grow = rowg0 + r;
        if (grow < N_NODES) {
            const float* p = xs[w] + r * 68 + g * 8;
            uint4 u;
            u.x = f2bf(p[0]) | (f2bf(p[1]) << 16);
            u.y = f2bf(p[2]) | (f2bf(p[3]) << 16);
            u.z = f2bf(p[4]) | (f2bf(p[5]) << 16);
            u.w = f2bf(p[6]) | (f2bf(p[7]) << 16);
            *(uint4*)(hb + (size_t)grow * HID + g * 8) = u;
        }
    }
}

// ---------------------------------------------------------------------------
// Fused GAT aggregate: 8 lanes per dst, 8 dsts per wave (degree-sorted).
// ---------------------------------------------------------------------------
template <bool RELU>
__global__ __launch_bounds__(256) void k_gat_agg(const int* __restrict__ rowptr,
        const int* __restrict__ col, const unsigned short* __restrict__ hb,
        const float* __restrict__ as_, const float* __restrict__ ad_,
        const float* __restrict__ bias, const int* __restrict__ nodeord,
        unsigned short* __restrict__ outb) {
    int t = threadIdx.x;
    int lane = t & 63;
    int wid = blockIdx.x * 4 + (t >> 6);
    int l8 = lane & 7;
    int ch = l8 * 8;
    int d = nodeord[wid * 8 + (lane >> 3)];
    int beg = rowptr[d];
    int deg = rowptr[d + 1] - beg;
    float add = ad_[d];
    int degw = deg;
    degw = max(degw, __shfl_xor(degw, 8, 64));
    degw = max(degw, __shfl_xor(degw, 16, 64));
    degw = max(degw, __shfl_xor(degw, 32, 64));

    float a0=0.f,a1=0.f,a2=0.f,a3=0.f,a4=0.f,a5=0.f,a6=0.f,a7=0.f,den=0.f;
    const unsigned short* hch = hb + ch;
    for (int c = 0; c < degw; c += 8) {
        int idx = c + l8;
        int sj = 0; float wj = 0.f;
        if (idx < deg) {
            sj = col[beg + idx];
            float e = as_[sj] + add;
            e = (e > 0.f) ? e : NEG_SLOPE * e;
            wj = __expf(e);
        }
        #pragma unroll
        for (int j = 0; j < 8; ++j) {
            int sl = (lane & 56) | j;
            int   s  = __shfl(sj, sl, 64);
            float w0 = __shfl(wj, sl, 64);   // 0 for padded slots
            den += w0;
            uint4 hv = *(const uint4*)(hch + (size_t)s * HID);
            a0 = fmaf(w0, __uint_as_float(hv.x << 16),         a0);
            a1 = fmaf(w0, __uint_as_float(hv.x & 0xffff0000u), a1);
            a2 = fmaf(w0, __uint_as_float(hv.y << 16),         a2);
            a3 = fmaf(w0, __uint_as_float(hv.y & 0xffff0000u), a3);
            a4 = fmaf(w0, __uint_as_float(hv.z << 16),         a4);
            a5 = fmaf(w0, __uint_as_float(hv.z & 0xffff0000u), a5);
            a6 = fmaf(w0, __uint_as_float(hv.w << 16),         a6);
            a7 = fmaf(w0, __uint_as_float(hv.w & 0xffff0000u), a7);
        }
    }
    float inv = 1.f / (den + 1e-16f);
    float4 bA = *(const float4*)(bias + ch);
    float4 bB = *(const float4*)(bias + ch + 4);
    float o0 = fmaf(a0, inv, bA.x), o1 = fmaf(a1, inv, bA.y);
    float o2 = fmaf(a2, inv, bA.z), o3 = fmaf(a3, inv, bA.w);
    float o4 = fmaf(a4, inv, bB.x), o5 = fmaf(a5, inv, bB.y);
    float o6 = fmaf(a6, inv, bB.z), o7 = fmaf(a7, inv, bB.w);
    if (RELU) {
        o0 = fmaxf(o0, 0.f); o1 = fmaxf(o1, 0.f);
        o2 = fmaxf(o2, 0.f); o3 = fmaxf(o3, 0.f);
        o4 = fmaxf(o4, 0.f); o5 = fmaxf(o5, 0.f);
        o6 = fmaxf(o6, 0.f); o7 = fmaxf(o7, 0.f);
    }
    uint4 u;
    u.x = f2bf(o0) | (f2bf(o1) << 16);
    u.y = f2bf(o2) | (f2bf(o3) << 16);
    u.z = f2bf(o4) | (f2bf(o5) << 16);
    u.w = f2bf(o6) | (f2bf(o7) << 16);
    *(uint4*)(outb + (size_t)d * HID + ch) = u;
}

// ---------------------------------------------------------------------------
// logits = aggb @ W2 + b2 (MFMA bf16, N padded to 48) ; out = log_softmax.
// ---------------------------------------------------------------------------
__global__ __launch_bounds__(256) void k_final(
        const unsigned short* __restrict__ aggb,
        const unsigned short* __restrict__ W2t, const float* __restrict__ b2,
        float* __restrict__ out) {
    __shared__ float xs[64 * 44];
    int t = threadIdx.x;
    int lane = t & 63, w = t >> 6;
    int quad = lane >> 4, lr = lane & 15;
    int rowg0 = blockIdx.x * 64 + w * 16;
    int base = blockIdx.x * 64;
    int rem = N_NODES - base; if (rem > 64) rem = 64;

    bf16x8 bfr[2][3];
    #pragma unroll
    for (int kc = 0; kc < 2; ++kc)
        #pragma unroll
        for (int nt = 0; nt < 3; ++nt)
            bfr[kc][nt] = *(const bf16x8*)(W2t + (nt * 16 + lr) * HID
                                           + kc * 32 + quad * 8);
    f32x4 zero = {0.f, 0.f, 0.f, 0.f};
    f32x4 acc[3] = {zero, zero, zero};
    int arow = rowg0 + lr; if (arow >= N_NODES) arow = N_NODES - 1;
    #pragma unroll
    for (int kc = 0; kc < 2; ++kc) {
        bf16x8 af = *(const bf16x8*)(aggb + (size_t)arow * HID
                                     + kc * 32 + quad * 8);
        #pragma unroll
        for (int nt = 0; nt < 3; ++nt)
            acc[nt] = __builtin_amdgcn_mfma_f32_16x16x32_bf16(
                          af, bfr[kc][nt], acc[nt], 0, 0, 0);
    }
    float bc[3];
    #pragma unroll
    for (int nt = 0; nt < 3; ++nt) {
        int cl = nt * 16 + lr;
        bc[nt] = (cl < N_CLASS) ? b2[cl] : -1e30f;
    }
    #pragma unroll
    for (int reg = 0; reg < 4; ++reg) {
        float v0 = acc[0][reg] + bc[0];
        float v1 = acc[1][reg] + bc[1];
        float v2 = acc[2][reg] + bc[2];
        float m = fmaxf(fmaxf(v0, v1), v2);
        #pragma unroll
        for (int off = 1; off < 16; off <<= 1)
            m = fmaxf(m, __shfl_xor(m, off, 64));
        float ss = __expf(v0 - m) + __expf(v1 - m) + __expf(v2 - m);
        #pragma unroll
        for (int off = 1; off < 16; off <<= 1)
            ss += __shfl_xor(ss, off, 64);
        float lse = m + logf(ss);
        int r = w * 16 + quad * 4 + reg;
        xs[r * 44 + lr]      = v0 - lse;
        xs[r * 44 + 16 + lr] = v1 - lse;
        if (lr < 8) xs[r * 44 + 32 + lr] = v2 - lse;
    }
    __syncthreads();
    #pragma unroll
    for (int j = 0; j < 3; ++j) {
        int idx = j * 256 + t;             // float4 index, 10 per row
        if (idx < rem * 10) {
            int r = idx / 10, c4 = idx - r * 10;
            float4 v = *(const float4*)(xs + r * 44 + c4 * 4);
            *(float4*)(out + (size_t)base * N_CLASS + idx * 4) = v;
        }
    }
}

// ---------------------------------------------------------------------------
extern "C" void kernel_launch(void* const* d_in, const int* in_sizes, int n_in,
                              void* d_out, int out_size, void* d_ws, size_t ws_size,
                              hipStream_t stream) {
    const float* x     = (const float*)d_in[0];
    const int*   ei    = (const int*)  d_in[1];
    const float* W1    = (const float*)d_in[2];
    const float* b1    = (const float*)d_in[3];
    const float* Wc0   = (const float*)d_in[4];
    const float* as0   = (const float*)d_in[5];
    const float* ad0   = (const float*)d_in[6];
    const float* bias0 = (const float*)d_in[7];
    const float* Wc1   = (const float*)d_in[8];
    const float* as1   = (const float*)d_in[9];
    const float* ad1   = (const float*)d_in[10];
    const float* bias1 = (const float*)d_in[11];
    const float* W2    = (const float*)d_in[12];
    const float* b2    = (const float*)d_in[13];
    float* out = (float*)d_out;

    // ---- workspace layout (~50 MB) ----
    // hb and buf1 are live CONCURRENTLY (fat kernel) -> separate regions.
    // agg1b overlays buf1+buf2 (partition buffers dead by the time agg1 runs).
    char* p = (char*)d_ws;
    unsigned short* hb    = (unsigned short*)p; p += (size_t)N_NODES * HID * 2;
    unsigned short* agg0b = (unsigned short*)p; p += (size_t)N_NODES * HID * 2;
    char* pbuf = p;
    unsigned int*   buf1  = (unsigned int*)pbuf;
    unsigned int*   buf2  = (unsigned int*)(pbuf + (size_t)NCB * CAP1 * 4);
    unsigned short* agg1b = (unsigned short*)pbuf;     // 12.8MB <= 16.47MB
    p += (size_t)NCB * CAP1 * 4 + (size_t)NFB * CAPF * 4;
    int* col = (int*)p;                          p += (size_t)ET * 4;
    unsigned short* Wt1  = (unsigned short*)p;   p += F_IN * HID * 2;
    unsigned short* Wtc0 = (unsigned short*)p;   p += HID * HID * 2;
    unsigned short* Wtc1 = (unsigned short*)p;   p += HID * HID * 2;
    unsigned short* W2t  = (unsigned short*)p;   p += 48 * HID * 2;
    float* as_ = (float*)p;                      p += (size_t)N_NODES * 4;
    float* ad_ = (float*)p;                      p += (size_t)N_NODES * 4;
    // contiguous zero block: tail1, fcnt, fbase, dhist, dbase, done[2]
    int* tail1 = (int*)p;
    int* fcnt  = tail1 + NCB;
    int* fbase = fcnt + NFB;
    int* dhist = fbase + NFB;
    int* dbase = dhist + 64;
    int* done  = dbase + 64;                     // done[0]=part2, done[1]=part3
    const int ZCOUNT = NCB + 2 * NFB + 128 + 2;  // 1701
    p += (size_t)ZCOUNT * 4;
    int* rowptr  = (int*)p;                      p += (size_t)(N_NODES + 1) * 4;
    int* nodeord = (int*)p;

    const int AGG_BLOCKS  = N_NODES / 32;        // 3125: 4 waves x 8 dsts
    const int NODE_BLOCKS = (N_NODES + 255) / 256;

    // prep (weights bf16-T + zero counters)
    k_prepw<<<32, 256, 0, stream>>>(W1, Wc0, Wc1, W2, Wt1, Wtc0, Wtc1, W2t,
                                    tail1, ZCOUNT);
    // FAT: part1 (831 blocks) || fused lin1+GAT0 gemm/att (1563 blocks)
    k_p1lin<<<NT1 + ROW_BLOCKS, 256, 0, stream>>>(
        ei, tail1, buf1, x, Wt1, b1, Wtc0, as0, ad0, hb, as_, ad_);
    // level-2 partition (+ inlined fine scan in last block)
    k_part2<<<NCB * BPC, 256, 0, stream>>>(buf1, tail1, fcnt, buf2, fbase,
                                           rowptr, done + 0);
    // level-3 partition -> CSR (+ inlined degree scan in last block)
    k_part3<<<NFB, 256, 0, stream>>>(buf2, fcnt, fbase, rowptr, col, dhist,
                                     dbase, done + 1);
    k_dscatter<<<NODE_BLOCKS, 256, 0, stream>>>(rowptr, dbase, nodeord);

    // GAT layer 0 aggregate
    k_gat_agg<true><<<AGG_BLOCKS, 256, 0, stream>>>(
        rowptr, col, hb, as_, ad_, bias0, nodeord, agg0b);

    // GAT layer 1
    k_gemm_att<<<ROW_BLOCKS, 256, 0, stream>>>(agg0b, Wtc1, as1, ad1,
                                               hb, as_, ad_);
    k_gat_agg<false><<<AGG_BLOCKS, 256, 0, stream>>>(
        rowptr, col, hb, as_, ad_, bias1, nodeord, agg1b);

    // logits + log_softmax (MFMA)
    k_final<<<ROW_BLOCKS, 256, 0, stream>>>(agg1b, W2t, b2, out);
}

// Round 4
// 289.924 us; speedup vs baseline: 1.0792x; 1.0114x over previous
//
// R3 resubmission of the R2 experiment (R2/R3 failed at container acquisition,
// no kernel signal; source re-audited, identical semantics to R1-measured +
// load-hoisting in k_p1lin/k_gat_agg).
#include <hip/hip_runtime.h>

#define N_NODES 100000
#define N_EDGES 1600000
#define F_IN    128
#define HID     64
#define N_CLASS 40
#define NEG_SLOPE 0.2f
#define ET (N_EDGES + N_NODES)          // 1,700,000
#define ROW_BLOCKS ((N_NODES + 63) / 64)

// ---- 2-level radix partition geometry ----
#define NCB   7
#define CAP1  294912
#define BPC   144
#define NFB   782
#define CAPF  2624
#define NT1   ((ET + 2047) / 2048)

typedef __attribute__((ext_vector_type(8))) short bf16x8;
typedef __attribute__((ext_vector_type(4))) float f32x4;

__device__ __forceinline__ unsigned int f2bf(float f) {  // fp32 -> bf16 (RNE)
    unsigned int u = __float_as_uint(f);
    return (u + 0x7fffu + ((u >> 16) & 1u)) >> 16;
}

// ---------------------------------------------------------------------------
// Weight prep (bf16, transposed [n][k]) + zero-init of all counter arrays.
// ---------------------------------------------------------------------------
__global__ __launch_bounds__(256) void k_prepw(const float* __restrict__ W1,
        const float* __restrict__ Wc0, const float* __restrict__ Wc1,
        const float* __restrict__ W2,
        unsigned short* __restrict__ Wt1, unsigned short* __restrict__ Wtc0,
        unsigned short* __restrict__ Wtc1, unsigned short* __restrict__ W2t,
        int* __restrict__ zbuf, int zcount) {
    int g = blockIdx.x * 256 + threadIdx.x;
    int stride = gridDim.x * 256;
    for (int i = g; i < zcount; i += stride) zbuf[i] = 0;
    for (int i = g; i < F_IN * HID; i += stride) {
        int k = i >> 6, n = i & 63;
        Wt1[n * F_IN + k] = (unsigned short)f2bf(W1[i]);
    }
    for (int i = g; i < HID * HID; i += stride) {
        int k = i >> 6, n = i & 63;
        Wtc0[n * HID + k] = (unsigned short)f2bf(Wc0[i]);
        Wtc1[n * HID + k] = (unsigned short)f2bf(Wc1[i]);
    }
    for (int i = g; i < 48 * HID; i += stride) {
        int n = i >> 6, k = i & 63;
        W2t[n * HID + k] = (n < N_CLASS)
            ? (unsigned short)f2bf(W2[k * N_CLASS + n]) : (unsigned short)0;
    }
}

// ---------------------------------------------------------------------------
// FAT KERNEL: blocks [0, NT1) run partition level 1; blocks
// [NT1, NT1+ROW_BLOCKS) run the fused lin1 + GAT-0 gemm/att.
// lin1 branch: ALL 8 x-loads hoisted into registers before the convert/MFMA
// phase (8 outstanding loads/wave instead of 1-2; was latency-bound at 48
// VGPRs).
// ---------------------------------------------------------------------------
__global__ __launch_bounds__(256) void k_p1lin(
        const int* __restrict__ ei, int* __restrict__ tail1,
        unsigned int* __restrict__ buf1,
        const float* __restrict__ x, const unsigned short* __restrict__ Wt1,
        const float* __restrict__ b1, const unsigned short* __restrict__ Wtc0,
        const float* __restrict__ att_s, const float* __restrict__ att_d,
        unsigned short* __restrict__ hb, float* __restrict__ as_,
        float* __restrict__ ad_) {
    __shared__ __align__(16) char smem[17408];   // union: eb[2048] u32 | xs 4x1088 f32
    __shared__ int hist[NCB], lb[NCB], cbase[NCB];
    int t = threadIdx.x;
    int lane = t & 63, w = t >> 6;

    if (blockIdx.x < NT1) {
        // ---------------- part1: edges -> 7 coarse buckets (dst>>14) -------
        unsigned int* eb = (unsigned int*)smem;
        int tileBase = blockIdx.x * 2048;
        int total = ET - tileBase; if (total > 2048) total = 2048;
        if (t < NCB) hist[t] = 0;
        __syncthreads();
        unsigned long long ltm = (1ull << lane) - 1ull;
        unsigned int pk[8]; int ps[8];
        #pragma unroll
        for (int r = 0; r < 8; ++r) {
            int i = tileBase + r * 256 + t;
            int s = 0, d = 0;
            bool valid = (i < ET);
            if (valid) {
                if (i < N_EDGES) { s = ei[i]; d = ei[N_EDGES + i]; }
                else             { s = d = i - N_EDGES; }
            }
            int b = valid ? (d >> 14) : -1;
            unsigned long long m[NCB];
            #pragma unroll
            for (int q = 0; q < NCB; ++q) m[q] = __ballot(b == q);
            int cnt = 0;
            #pragma unroll
            for (int q = 0; q < NCB; ++q) if (lane == q) cnt = __popcll(m[q]);
            int old = 0;
            if (lane < NCB) old = atomicAdd(&hist[lane], cnt);
            int bsafe = valid ? b : 0;
            int basew = __shfl(old, bsafe, 64);
            if (valid) {
                int rank = 0;
                #pragma unroll
                for (int q = 0; q < NCB; ++q)
                    if (b == q) rank = (int)__popcll(m[q] & ltm);
                pk[r] = ((unsigned int)s << 14) | ((unsigned int)d & 16383u);
                ps[r] = (basew + rank) | (b << 12);
            } else ps[r] = -1;
        }
        __syncthreads();
        if (t == 0) {
            int run = 0;
            #pragma unroll
            for (int q = 0; q < NCB; ++q) { int h = hist[q]; lb[q] = run; run += h; }
        }
        __syncthreads();
        if (t < NCB) {
            int g = (hist[t] > 0) ? atomicAdd(&tail1[t], hist[t]) : 0;
            cbase[t] = g - lb[t];
        }
        #pragma unroll
        for (int r = 0; r < 8; ++r) {
            if (ps[r] >= 0) {
                int b = ps[r] >> 12, pos = ps[r] & 4095;
                eb[lb[b] + pos] = pk[r];
            }
        }
        __syncthreads();
        int B1 = lb[1], B2 = lb[2], B3 = lb[3], B4 = lb[4], B5 = lb[5], B6 = lb[6];
        for (int j = t; j < total; j += 256) {
            unsigned int p = eb[j];
            int b = (j >= B1) + (j >= B2) + (j >= B3) + (j >= B4)
                  + (j >= B5) + (j >= B6);
            buf1[(size_t)b * CAP1 + cbase[b] + j] = p;
        }
    } else {
        // -------- fused lin1 + GAT-0 gemm/att (unchanged numerics) --------
        int quad = lane >> 4, lr = lane & 15;
        int rowg0 = (int)(blockIdx.x - NT1) * 64 + w * 16;
        float* xs = (float*)smem + w * (16 * 68);

        // GEMM 1: h0 = relu(x@W1+b1), K=128.
        // Hoist ALL x loads first -> 8 outstanding global loads per lane.
        int arow = rowg0 + lr; if (arow >= N_NODES) arow = N_NODES - 1;
        const float* ab = x + (size_t)arow * F_IN + quad * 8;
        float4 xa[8];
        #pragma unroll
        for (int kc = 0; kc < 4; ++kc) {
            xa[2 * kc]     = *(const float4*)(ab + kc * 32);
            xa[2 * kc + 1] = *(const float4*)(ab + kc * 32 + 4);
        }
        f32x4 zero = {0.f, 0.f, 0.f, 0.f};
        f32x4 acc[4] = {zero, zero, zero, zero};
        #pragma unroll
        for (int kc = 0; kc < 4; ++kc) {
            bf16x8 bw[4];
            #pragma unroll
            for (int nt = 0; nt < 4; ++nt)
                bw[nt] = *(const bf16x8*)(Wt1 + (nt * 16 + lr) * F_IN
                                          + kc * 32 + quad * 8);
            float4 a0 = xa[2 * kc], a1 = xa[2 * kc + 1];
            union { bf16x8 v; unsigned int u[4]; } af;
            af.u[0] = f2bf(a0.x) | (f2bf(a0.y) << 16);
            af.u[1] = f2bf(a0.z) | (f2bf(a0.w) << 16);
            af.u[2] = f2bf(a1.x) | (f2bf(a1.y) << 16);
            af.u[3] = f2bf(a1.z) | (f2bf(a1.w) << 16);
            #pragma unroll
            for (int nt = 0; nt < 4; ++nt)
                acc[nt] = __builtin_amdgcn_mfma_f32_16x16x32_bf16(
                              af.v, bw[nt], acc[nt], 0, 0, 0);
        }
        #pragma unroll
        for (int nt = 0; nt < 4; ++nt) {
            float bv = b1[nt * 16 + lr];
            #pragma unroll
            for (int reg = 0; reg < 4; ++reg)
                xs[(quad * 4 + reg) * 68 + nt * 16 + lr] =
                    fmaxf(acc[nt][reg] + bv, 0.f);
        }
        // GEMM 2: h = h0@Wc0, K=64, A from LDS (wave-local, no barriers)
        f32x4 acc2[4] = {zero, zero, zero, zero};
        #pragma unroll
        for (int kc = 0; kc < 2; ++kc) {
            bf16x8 bw[4];
            #pragma unroll
            for (int nt = 0; nt < 4; ++nt)
                bw[nt] = *(const bf16x8*)(Wtc0 + (nt * 16 + lr) * HID
                                          + kc * 32 + quad * 8);
            const float* ap = xs + lr * 68 + kc * 32 + quad * 8;
            float4 a0 = *(const float4*)ap;
            float4 a1 = *(const float4*)(ap + 4);
            union { bf16x8 v; unsigned int u[4]; } af;
            af.u[0] = f2bf(a0.x) | (f2bf(a0.y) << 16);
            af.u[1] = f2bf(a0.z) | (f2bf(a0.w) << 16);
            af.u[2] = f2bf(a1.x) | (f2bf(a1.y) << 16);
            af.u[3] = f2bf(a1.z) | (f2bf(a1.w) << 16);
            #pragma unroll
            for (int nt = 0; nt < 4; ++nt)
                acc2[nt] = __builtin_amdgcn_mfma_f32_16x16x32_bf16(
                              af.v, bw[nt], acc2[nt], 0, 0, 0);
        }
        float asv[4], adv[4];
        #pragma unroll
        for (int nt = 0; nt < 4; ++nt) {
            asv[nt] = att_s[nt * 16 + lr];
            adv[nt] = att_d[nt * 16 + lr];
        }
        #pragma unroll
        for (int reg = 0; reg < 4; ++reg) {
            float p1 = acc2[0][reg] * asv[0] + acc2[1][reg] * asv[1]
                     + acc2[2][reg] * asv[2] + acc2[3][reg] * asv[3];
            float p2 = acc2[0][reg] * adv[0] + acc2[1][reg] * adv[1]
                     + acc2[2][reg] * adv[2] + acc2[3][reg] * adv[3];
            #pragma unroll
            for (int off = 1; off < 16; off <<= 1) {
                p1 += __shfl_xor(p1, off, 64);
                p2 += __shfl_xor(p2, off, 64);
            }
            if (lr == 0) {
                int grow = rowg0 + quad * 4 + reg;
                if (grow < N_NODES) { as_[grow] = p1; ad_[grow] = p2; }
            }
        }
        #pragma unroll
        for (int nt = 0; nt < 4; ++nt)
            #pragma unroll
            for (int reg = 0; reg < 4; ++reg)
                xs[(quad * 4 + reg) * 68 + nt * 16 + lr] = acc2[nt][reg];
        #pragma unroll
        for (int j = 0; j < 2; ++j) {
            int task = j * 64 + lane;
            int r = task >> 3, g = task & 7;
            int grow = rowg0 + r;
            if (grow < N_NODES) {
                const float* p = xs + r * 68 + g * 8;
                uint4 u;
                u.x = f2bf(p[0]) | (f2bf(p[1]) << 16);
                u.y = f2bf(p[2]) | (f2bf(p[3]) << 16);
                u.z = f2bf(p[4]) | (f2bf(p[5]) << 16);
                u.w = f2bf(p[6]) | (f2bf(p[7]) << 16);
                *(uint4*)(hb + (size_t)grow * HID + g * 8) = u;
            }
        }
    }
}

// ---------------------------------------------------------------------------
// Partition level 2: coarse bucket -> 128 fine buckets. Packed uint payload.
// Last finishing block performs the fine-bucket exclusive scan.
// ---------------------------------------------------------------------------
__global__ __launch_bounds__(256) void k_part2(const unsigned int* __restrict__ buf1,
        const int* __restrict__ tail1, int* __restrict__ fcnt,
        unsigned int* __restrict__ buf2, int* __restrict__ fbase,
        int* __restrict__ rowptr, int* __restrict__ done0) {
    __shared__ unsigned int eb[2048];
    __shared__ int hist[128], lbase[128], loff[128], goff[128], sc[128];
    __shared__ int lastflag, wsum4[4];
    int t = threadIdx.x;
    int cb   = blockIdx.x / BPC;
    int tile = blockIdx.x % BPC;
    int n1 = tail1[cb];
    int base = tile * 2048;
    if (base < n1) {
        int total = n1 - base; if (total > 2048) total = 2048;
        if (t < 128) hist[t] = 0;
        __syncthreads();
        unsigned int pr[8]; int fr[8];
        #pragma unroll
        for (int r = 0; r < 8; ++r) {
            int i = base + r * 256 + t;
            int f = -1; unsigned int p = 0;
            if (i < n1) {
                p = buf1[(size_t)cb * CAP1 + i];
                f = (int)((p >> 7) & 127u);
                atomicAdd(&hist[f], 1);
            }
            pr[r] = p; fr[r] = f;
        }
        __syncthreads();
        if (t < 128) sc[t] = hist[t];
        __syncthreads();
        for (int off = 1; off < 128; off <<= 1) {
            int u = (t < 128 && t >= off) ? sc[t - off] : 0;
            __syncthreads();
            if (t < 128) sc[t] += u;
            __syncthreads();
        }
        if (t < 128) { lbase[t] = sc[t] - hist[t]; loff[t] = 0; }
        __syncthreads();
        if (t < 128 && hist[t] > 0)
            goff[t] = atomicAdd(&fcnt[cb * 128 + t], hist[t]);
        #pragma unroll
        for (int r = 0; r < 8; ++r) {
            if (fr[r] >= 0) {
                int f = fr[r];
                int pos = lbase[f] + atomicAdd(&loff[f], 1);
                eb[pos] = (pr[r] & 127u) | ((pr[r] >> 14) << 7)
                        | ((unsigned int)f << 24);
            }
        }
        __syncthreads();
        for (int j = t; j < total; j += 256) {
            unsigned int q = eb[j];
            int f = (int)(q >> 24);
            buf2[(size_t)(cb * 128 + f) * CAPF + goff[f] + (j - lbase[f])] =
                q & 0xFFFFFFu;
        }
    }
    // ---- done-ticket: last block of the grid runs the fine scan ----
    if (t == 0) lastflag = (atomicAdd(done0, 1) == NCB * BPC - 1);
    __syncthreads();
    if (lastflag) {
        __threadfence();
        int k0 = t * 4;
        int v0 = (k0     < NFB) ? fcnt[k0]     : 0;
        int v1 = (k0 + 1 < NFB) ? fcnt[k0 + 1] : 0;
        int v2 = (k0 + 2 < NFB) ? fcnt[k0 + 2] : 0;
        int v3 = (k0 + 3 < NFB) ? fcnt[k0 + 3] : 0;
        int s1 = v0 + v1, s2 = s1 + v2, s3 = s2 + v3;
        int lane = t & 63, w = t >> 6;
        int ws = s3;
        #pragma unroll
        for (int off = 1; off < 64; off <<= 1) {
            int u = __shfl_up(ws, off, 64);
            if (lane >= off) ws += u;
        }
        if (lane == 63) wsum4[w] = ws;
        __syncthreads();
        int wb = 0;
        #pragma unroll
        for (int q = 0; q < 4; ++q) if (q < w) wb += wsum4[q];
        int ex = wb + ws - s3;
        if (k0     < NFB) fbase[k0]     = ex;
        if (k0 + 1 < NFB) fbase[k0 + 1] = ex + v0;
        if (k0 + 2 < NFB) fbase[k0 + 2] = ex + s1;
        if (k0 + 3 < NFB) fbase[k0 + 3] = ex + s2;
        if (t == 0) rowptr[N_NODES] = ET;
    }
}

// ---------------------------------------------------------------------------
// Partition level 3: fine bucket -> exact per-node CSR + degree histogram.
// Last finishing block performs the 64-entry degree scan.
// ---------------------------------------------------------------------------
__global__ __launch_bounds__(256) void k_part3(const unsigned int* __restrict__ buf2,
        const int* __restrict__ fcnt, const int* __restrict__ fbase,
        int* __restrict__ rowptr, int* __restrict__ col,
        int* __restrict__ dhistg, int* __restrict__ dbase,
        int* __restrict__ done1) {
    __shared__ unsigned int eb[CAPF];
    __shared__ int cs[CAPF];
    __shared__ int hist[128], lbase[128], loff[128], sc[128], dh[64];
    __shared__ int lastflag;
    int t = threadIdx.x;
    int fb = blockIdx.x;
    int nF = fcnt[fb];
    int gb = fbase[fb];
    int nbase = fb * 128;
    if (t < 128) hist[t] = 0;
    if (t >= 128 && t < 192) dh[t - 128] = 0;
    __syncthreads();
    for (int j = t; j < nF; j += 256) {
        unsigned int q = buf2[(size_t)fb * CAPF + j];
        eb[j] = q;
        atomicAdd(&hist[q & 127u], 1);
    }
    __syncthreads();
    if (t < 128) sc[t] = hist[t];
    __syncthreads();
    for (int off = 1; off < 128; off <<= 1) {
        int u = (t < 128 && t >= off) ? sc[t - off] : 0;
        __syncthreads();
        if (t < 128) sc[t] += u;
        __syncthreads();
    }
    if (t < 128) { lbase[t] = sc[t] - hist[t]; loff[t] = 0; }
    __syncthreads();
    if (t < 128 && nbase + t < N_NODES) {
        rowptr[nbase + t] = gb + lbase[t];
        int dg = hist[t]; if (dg > 63) dg = 63;
        atomicAdd(&dh[dg], 1);
    }
    for (int j = t; j < nF; j += 256) {
        unsigned int q = eb[j];
        int r = (int)(q & 127u);
        int p = lbase[r] + atomicAdd(&loff[r], 1);
        cs[p] = (int)(q >> 7);
    }
    __syncthreads();
    for (int j = t; j < nF; j += 256) col[gb + j] = cs[j];
    if (t < 64 && dh[t] > 0) atomicAdd(&dhistg[t], dh[t]);
    __syncthreads();
    // ---- done-ticket: last block runs the degree scan ----
    if (t == 0) lastflag = (atomicAdd(done1, 1) == NFB - 1);
    __syncthreads();
    if (lastflag && t < 64) {
        __threadfence();
        int v = dhistg[t];
        int s = v;
        #pragma unroll
        for (int off = 1; off < 64; off <<= 1) {
            int u = __shfl_up(s, off, 64);
            if (t >= off) s += u;
        }
        dbase[t] = s - v;   // exclusive
    }
}

// ---------------------------------------------------------------------------
__global__ __launch_bounds__(256) void k_dscatter(const int* __restrict__ rowptr,
        int* __restrict__ dbase, int* __restrict__ nodeord) {
    __shared__ int lh[64], goff[64];
    int t = threadIdx.x;
    if (t < 64) lh[t] = 0;
    __syncthreads();
    int i = blockIdx.x * 256 + t;
    int deg = -1, lrank = 0;
    if (i < N_NODES) {
        deg = rowptr[i + 1] - rowptr[i];
        if (deg > 63) deg = 63;
        lrank = atomicAdd(&lh[deg], 1);
    }
    __syncthreads();
    if (t < 64) goff[t] = (lh[t] > 0) ? atomicAdd(&dbase[t], lh[t]) : 0;
    __syncthreads();
    if (deg >= 0) nodeord[goff[deg] + lrank] = i;
}

// ---------------------------------------------------------------------------
// h = hin @ Wc (MFMA, bf16 in/out) ; as_/ad_ att dots. (layer 1)
// ---------------------------------------------------------------------------
__global__ __launch_bounds__(256) void k_gemm_att(
        const unsigned short* __restrict__ hin,
        const unsigned short* __restrict__ Wt,
        const float* __restrict__ att_s, const float* __restrict__ att_d,
        unsigned short* __restrict__ hb, float* __restrict__ as_,
        float* __restrict__ ad_) {
    __shared__ float xs[4][16 * 68];
    int t = threadIdx.x;
    int lane = t & 63, w = t >> 6;
    int quad = lane >> 4, lr = lane & 15;
    int rowg0 = blockIdx.x * 64 + w * 16;

    bf16x8 bfr[2][4];
    #pragma unroll
    for (int kc = 0; kc < 2; ++kc)
        #pragma unroll
        for (int nt = 0; nt < 4; ++nt)
            bfr[kc][nt] = *(const bf16x8*)(Wt + (nt * 16 + lr) * HID
                                           + kc * 32 + quad * 8);
    f32x4 zero = {0.f, 0.f, 0.f, 0.f};
    f32x4 acc[4] = {zero, zero, zero, zero};

    int arow = rowg0 + lr; if (arow >= N_NODES) arow = N_NODES - 1;
    #pragma unroll
    for (int kc = 0; kc < 2; ++kc) {
        bf16x8 af = *(const bf16x8*)(hin + (size_t)arow * HID
                                     + kc * 32 + quad * 8);
        #pragma unroll
        for (int nt = 0; nt < 4; ++nt)
            acc[nt] = __builtin_amdgcn_mfma_f32_16x16x32_bf16(
                          af, bfr[kc][nt], acc[nt], 0, 0, 0);
    }
    float asv[4], adv[4];
    #pragma unroll
    for (int nt = 0; nt < 4; ++nt) {
        asv[nt] = att_s[nt * 16 + lr];
        adv[nt] = att_d[nt * 16 + lr];
    }
    #pragma unroll
    for (int reg = 0; reg < 4; ++reg) {
        float p1 = acc[0][reg] * asv[0] + acc[1][reg] * asv[1]
                 + acc[2][reg] * asv[2] + acc[3][reg] * asv[3];
        float p2 = acc[0][reg] * adv[0] + acc[1][reg] * adv[1]
                 + acc[2][reg] * adv[2] + acc[3][reg] * adv[3];
        #pragma unroll
        for (int off = 1; off < 16; off <<= 1) {
            p1 += __shfl_xor(p1, off, 64);
            p2 += __shfl_xor(p2, off, 64);
        }
        if (lr == 0) {
            int grow = rowg0 + quad * 4 + reg;
            if (grow < N_NODES) { as_[grow] = p1; ad_[grow] = p2; }
        }
    }
    #pragma unroll
    for (int nt = 0; nt < 4; ++nt)
        #pragma unroll
        for (int reg = 0; reg < 4; ++reg)
            xs[w][(quad * 4 + reg) * 68 + nt * 16 + lr] = acc[nt][reg];
    #pragma unroll
    for (int j = 0; j < 2; ++j) {
        int task = j * 64 + lane;
        int r = task >> 3, g = task & 7;
        int grow = rowg0 + r;
        if (grow < N_NODES) {
            const float* p = xs[w] + r * 68 + g * 8;
            uint4 u;
            u.x = f2bf(p[0]) | (f2bf(p[1]) << 16);
            u.y = f2bf(p[2]) | (f2bf(p[3]) << 16);
            u.z = f2bf(p[4]) | (f2bf(p[5]) << 16);
            u.w = f2bf(p[6]) | (f2bf(p[7]) << 16);
            *(uint4*)(hb + (size_t)grow * HID + g * 8) = u;
        }
    }
}

// ---------------------------------------------------------------------------
// Fused GAT aggregate: 8 lanes per dst, 8 dsts per wave (degree-sorted).
// Inner loop split into {8 shuffles + 8 gathers issued back-to-back} then
// {8 FMA blocks}: 8 outstanding L2 gathers per wave (was 1, latency-bound).
// ---------------------------------------------------------------------------
template <bool RELU>
__global__ __launch_bounds__(256) void k_gat_agg(const int* __restrict__ rowptr,
        const int* __restrict__ col, const unsigned short* __restrict__ hb,
        const float* __restrict__ as_, const float* __restrict__ ad_,
        const float* __restrict__ bias, const int* __restrict__ nodeord,
        unsigned short* __restrict__ outb) {
    int t = threadIdx.x;
    int lane = t & 63;
    int wid = blockIdx.x * 4 + (t >> 6);
    int l8 = lane & 7;
    int ch = l8 * 8;
    int d = nodeord[wid * 8 + (lane >> 3)];
    int beg = rowptr[d];
    int deg = rowptr[d + 1] - beg;
    float add = ad_[d];
    int degw = deg;
    degw = max(degw, __shfl_xor(degw, 8, 64));
    degw = max(degw, __shfl_xor(degw, 16, 64));
    degw = max(degw, __shfl_xor(degw, 32, 64));

    float a0=0.f,a1=0.f,a2=0.f,a3=0.f,a4=0.f,a5=0.f,a6=0.f,a7=0.f,den=0.f;
    const unsigned short* hch = hb + ch;
    for (int c = 0; c < degw; c += 8) {
        int idx = c + l8;
        int sj = 0; float wj = 0.f;
        if (idx < deg) {
            sj = col[beg + idx];
            float e = as_[sj] + add;
            e = (e > 0.f) ? e : NEG_SLOPE * e;
            wj = __expf(e);
        }
        uint4 hv[8]; float w0[8];
        #pragma unroll
        for (int j = 0; j < 8; ++j) {
            int sl = (lane & 56) | j;
            int s = __shfl(sj, sl, 64);
            w0[j] = __shfl(wj, sl, 64);      // 0 for padded slots
            hv[j] = *(const uint4*)(hch + (size_t)s * HID);
        }
        #pragma unroll
        for (int j = 0; j < 8; ++j) {
            den += w0[j];
            a0 = fmaf(w0[j], __uint_as_float(hv[j].x << 16),         a0);
            a1 = fmaf(w0[j], __uint_as_float(hv[j].x & 0xffff0000u), a1);
            a2 = fmaf(w0[j], __uint_as_float(hv[j].y << 16),         a2);
            a3 = fmaf(w0[j], __uint_as_float(hv[j].y & 0xffff0000u), a3);
            a4 = fmaf(w0[j], __uint_as_float(hv[j].z << 16),         a4);
            a5 = fmaf(w0[j], __uint_as_float(hv[j].z & 0xffff0000u), a5);
            a6 = fmaf(w0[j], __uint_as_float(hv[j].w << 16),         a6);
            a7 = fmaf(w0[j], __uint_as_float(hv[j].w & 0xffff0000u), a7);
        }
    }
    float inv = 1.f / (den + 1e-16f);
    float4 bA = *(const float4*)(bias + ch);
    float4 bB = *(const float4*)(bias + ch + 4);
    float o0 = fmaf(a0, inv, bA.x), o1 = fmaf(a1, inv, bA.y);
    float o2 = fmaf(a2, inv, bA.z), o3 = fmaf(a3, inv, bA.w);
    float o4 = fmaf(a4, inv, bB.x), o5 = fmaf(a5, inv, bB.y);
    float o6 = fmaf(a6, inv, bB.z), o7 = fmaf(a7, inv, bB.w);
    if (RELU) {
        o0 = fmaxf(o0, 0.f); o1 = fmaxf(o1, 0.f);
        o2 = fmaxf(o2, 0.f); o3 = fmaxf(o3, 0.f);
        o4 = fmaxf(o4, 0.f); o5 = fmaxf(o5, 0.f);
        o6 = fmaxf(o6, 0.f); o7 = fmaxf(o7, 0.f);
    }
    uint4 u;
    u.x = f2bf(o0) | (f2bf(o1) << 16);
    u.y = f2bf(o2) | (f2bf(o3) << 16);
    u.z = f2bf(o4) | (f2bf(o5) << 16);
    u.w = f2bf(o6) | (f2bf(o7) << 16);
    *(uint4*)(outb + (size_t)d * HID + ch) = u;
}

// ---------------------------------------------------------------------------
// logits = aggb @ W2 + b2 (MFMA bf16, N padded to 48) ; out = log_softmax.
// ---------------------------------------------------------------------------
__global__ __launch_bounds__(256) void k_final(
        const unsigned short* __restrict__ aggb,
        const unsigned short* __restrict__ W2t, const float* __restrict__ b2,
        float* __restrict__ out) {
    __shared__ float xs[64 * 44];
    int t = threadIdx.x;
    int lane = t & 63, w = t >> 6;
    int quad = lane >> 4, lr = lane & 15;
    int rowg0 = blockIdx.x * 64 + w * 16;
    int base = blockIdx.x * 64;
    int rem = N_NODES - base; if (rem > 64) rem = 64;

    bf16x8 bfr[2][3];
    #pragma unroll
    for (int kc = 0; kc < 2; ++kc)
        #pragma unroll
        for (int nt = 0; nt < 3; ++nt)
            bfr[kc][nt] = *(const bf16x8*)(W2t + (nt * 16 + lr) * HID
                                           + kc * 32 + quad * 8);
    f32x4 zero = {0.f, 0.f, 0.f, 0.f};
    f32x4 acc[3] = {zero, zero, zero};
    int arow = rowg0 + lr; if (arow >= N_NODES) arow = N_NODES - 1;
    #pragma unroll
    for (int kc = 0; kc < 2; ++kc) {
        bf16x8 af = *(const bf16x8*)(aggb + (size_t)arow * HID
                                     + kc * 32 + quad * 8);
        #pragma unroll
        for (int nt = 0; nt < 3; ++nt)
            acc[nt] = __builtin_amdgcn_mfma_f32_16x16x32_bf16(
                          af, bfr[kc][nt], acc[nt], 0, 0, 0);
    }
    float bc[3];
    #pragma unroll
    for (int nt = 0; nt < 3; ++nt) {
        int cl = nt * 16 + lr;
        bc[nt] = (cl < N_CLASS) ? b2[cl] : -1e30f;
    }
    #pragma unroll
    for (int reg = 0; reg < 4; ++reg) {
        float v0 = acc[0][reg] + bc[0];
        float v1 = acc[1][reg] + bc[1];
        float v2 = acc[2][reg] + bc[2];
        float m = fmaxf(fmaxf(v0, v1), v2);
        #pragma unroll
        for (int off = 1; off < 16; off <<= 1)
            m = fmaxf(m, __shfl_xor(m, off, 64));
        float ss = __expf(v0 - m) + __expf(v1 - m) + __expf(v2 - m);
        #pragma unroll
        for (int off = 1; off < 16; off <<= 1)
            ss += __shfl_xor(ss, off, 64);
        float lse = m + logf(ss);
        int r = w * 16 + quad * 4 + reg;
        xs[r * 44 + lr]      = v0 - lse;
        xs[r * 44 + 16 + lr] = v1 - lse;
        if (lr < 8) xs[r * 44 + 32 + lr] = v2 - lse;
    }
    __syncthreads();
    #pragma unroll
    for (int j = 0; j < 3; ++j) {
        int idx = j * 256 + t;             // float4 index, 10 per row
        if (idx < rem * 10) {
            int r = idx / 10, c4 = idx - r * 10;
            float4 v = *(const float4*)(xs + r * 44 + c4 * 4);
            *(float4*)(out + (size_t)base * N_CLASS + idx * 4) = v;
        }
    }
}

// ---------------------------------------------------------------------------
extern "C" void kernel_launch(void* const* d_in, const int* in_sizes, int n_in,
                              void* d_out, int out_size, void* d_ws, size_t ws_size,
                              hipStream_t stream) {
    const float* x     = (const float*)d_in[0];
    const int*   ei    = (const int*)  d_in[1];
    const float* W1    = (const float*)d_in[2];
    const float* b1    = (const float*)d_in[3];
    const float* Wc0   = (const float*)d_in[4];
    const float* as0   = (const float*)d_in[5];
    const float* ad0   = (const float*)d_in[6];
    const float* bias0 = (const float*)d_in[7];
    const float* Wc1   = (const float*)d_in[8];
    const float* as1   = (const float*)d_in[9];
    const float* ad1   = (const float*)d_in[10];
    const float* bias1 = (const float*)d_in[11];
    const float* W2    = (const float*)d_in[12];
    const float* b2    = (const float*)d_in[13];
    float* out = (float*)d_out;

    // ---- workspace layout (~50 MB) ----
    char* p = (char*)d_ws;
    unsigned short* hb    = (unsigned short*)p; p += (size_t)N_NODES * HID * 2;
    unsigned short* agg0b = (unsigned short*)p; p += (size_t)N_NODES * HID * 2;
    char* pbuf = p;
    unsigned int*   buf1  = (unsigned int*)pbuf;
    unsigned int*   buf2  = (unsigned int*)(pbuf + (size_t)NCB * CAP1 * 4);
    unsigned short* agg1b = (unsigned short*)pbuf;     // 12.8MB <= 16.47MB
    p += (size_t)NCB * CAP1 * 4 + (size_t)NFB * CAPF * 4;
    int* col = (int*)p;                          p += (size_t)ET * 4;
    unsigned short* Wt1  = (unsigned short*)p;   p += F_IN * HID * 2;
    unsigned short* Wtc0 = (unsigned short*)p;   p += HID * HID * 2;
    unsigned short* Wtc1 = (unsigned short*)p;   p += HID * HID * 2;
    unsigned short* W2t  = (unsigned short*)p;   p += 48 * HID * 2;
    float* as_ = (float*)p;                      p += (size_t)N_NODES * 4;
    float* ad_ = (float*)p;                      p += (size_t)N_NODES * 4;
    int* tail1 = (int*)p;
    int* fcnt  = tail1 + NCB;
    int* fbase = fcnt + NFB;
    int* dhist = fbase + NFB;
    int* dbase = dhist + 64;
    int* done  = dbase + 64;                     // done[0]=part2, done[1]=part3
    const int ZCOUNT = NCB + 2 * NFB + 128 + 2;  // 1701
    p += (size_t)ZCOUNT * 4;
    int* rowptr  = (int*)p;                      p += (size_t)(N_NODES + 1) * 4;
    int* nodeord = (int*)p;

    const int AGG_BLOCKS  = N_NODES / 32;        // 3125: 4 waves x 8 dsts
    const int NODE_BLOCKS = (N_NODES + 255) / 256;

    k_prepw<<<32, 256, 0, stream>>>(W1, Wc0, Wc1, W2, Wt1, Wtc0, Wtc1, W2t,
                                    tail1, ZCOUNT);
    k_p1lin<<<NT1 + ROW_BLOCKS, 256, 0, stream>>>(
        ei, tail1, buf1, x, Wt1, b1, Wtc0, as0, ad0, hb, as_, ad_);
    k_part2<<<NCB * BPC, 256, 0, stream>>>(buf1, tail1, fcnt, buf2, fbase,
                                           rowptr, done + 0);
    k_part3<<<NFB, 256, 0, stream>>>(buf2, fcnt, fbase, rowptr, col, dhist,
                                     dbase, done + 1);
    k_dscatter<<<NODE_BLOCKS, 256, 0, stream>>>(rowptr, dbase, nodeord);

    k_gat_agg<true><<<AGG_BLOCKS, 256, 0, stream>>>(
        rowptr, col, hb, as_, ad_, bias0, nodeord, agg0b);

    k_gemm_att<<<ROW_BLOCKS, 256, 0, stream>>>(agg0b, Wtc1, as1, ad1,
                                               hb, as_, ad_);
    k_gat_agg<false><<<AGG_BLOCKS, 256, 0, stream>>>(
        rowptr, col, hb, as_, ad_, bias1, nodeord, agg1b);

    k_final<<<ROW_BLOCKS, 256, 0, stream>>>(agg1b, W2t, b2, out);
}

// Round 5
// 286.529 us; speedup vs baseline: 1.0920x; 1.0118x over previous
//
// R4: force-issue loads with sched_barrier(0) fences (R3's source-level hoist
// was re-sunk by the scheduler: VGPR stayed 48). Fences in lin1 x-loads,
// part1 ei-loads, and gat_agg gather batch (+ next-chunk prelude pipeline).
#include <hip/hip_runtime.h>

#define N_NODES 100000
#define N_EDGES 1600000
#define F_IN    128
#define HID     64
#define N_CLASS 40
#define NEG_SLOPE 0.2f
#define ET (N_EDGES + N_NODES)          // 1,700,000
#define ROW_BLOCKS ((N_NODES + 63) / 64)

// ---- 2-level radix partition geometry ----
#define NCB   7
#define CAP1  294912
#define BPC   144
#define NFB   782
#define CAPF  2624
#define NT1   ((ET + 2047) / 2048)

typedef __attribute__((ext_vector_type(8))) short bf16x8;
typedef __attribute__((ext_vector_type(4))) float f32x4;

__device__ __forceinline__ unsigned int f2bf(float f) {  // fp32 -> bf16 (RNE)
    unsigned int u = __float_as_uint(f);
    return (u + 0x7fffu + ((u >> 16) & 1u)) >> 16;
}

// ---------------------------------------------------------------------------
// Weight prep (bf16, transposed [n][k]) + zero-init of all counter arrays.
// ---------------------------------------------------------------------------
__global__ __launch_bounds__(256) void k_prepw(const float* __restrict__ W1,
        const float* __restrict__ Wc0, const float* __restrict__ Wc1,
        const float* __restrict__ W2,
        unsigned short* __restrict__ Wt1, unsigned short* __restrict__ Wtc0,
        unsigned short* __restrict__ Wtc1, unsigned short* __restrict__ W2t,
        int* __restrict__ zbuf, int zcount) {
    int g = blockIdx.x * 256 + threadIdx.x;
    int stride = gridDim.x * 256;
    for (int i = g; i < zcount; i += stride) zbuf[i] = 0;
    for (int i = g; i < F_IN * HID; i += stride) {
        int k = i >> 6, n = i & 63;
        Wt1[n * F_IN + k] = (unsigned short)f2bf(W1[i]);
    }
    for (int i = g; i < HID * HID; i += stride) {
        int k = i >> 6, n = i & 63;
        Wtc0[n * HID + k] = (unsigned short)f2bf(Wc0[i]);
        Wtc1[n * HID + k] = (unsigned short)f2bf(Wc1[i]);
    }
    for (int i = g; i < 48 * HID; i += stride) {
        int n = i >> 6, k = i & 63;
        W2t[n * HID + k] = (n < N_CLASS)
            ? (unsigned short)f2bf(W2[k * N_CLASS + n]) : (unsigned short)0;
    }
}

// ---------------------------------------------------------------------------
// FAT KERNEL: blocks [0, NT1) run partition level 1; blocks
// [NT1, NT1+ROW_BLOCKS) run the fused lin1 + GAT-0 gemm/att.
// Both branches: loads issued in a block, then sched_barrier(0) so the
// scheduler cannot sink them into the dependent serial chain.
// ---------------------------------------------------------------------------
__global__ __launch_bounds__(256) void k_p1lin(
        const int* __restrict__ ei, int* __restrict__ tail1,
        unsigned int* __restrict__ buf1,
        const float* __restrict__ x, const unsigned short* __restrict__ Wt1,
        const float* __restrict__ b1, const unsigned short* __restrict__ Wtc0,
        const float* __restrict__ att_s, const float* __restrict__ att_d,
        unsigned short* __restrict__ hb, float* __restrict__ as_,
        float* __restrict__ ad_) {
    __shared__ __align__(16) char smem[17408];   // union: eb[2048] u32 | xs 4x1088 f32
    __shared__ int hist[NCB], lb[NCB], cbase[NCB];
    int t = threadIdx.x;
    int lane = t & 63, w = t >> 6;

    if (blockIdx.x < NT1) {
        // ---------------- part1: edges -> 7 coarse buckets (dst>>14) -------
        unsigned int* eb = (unsigned int*)smem;
        int tileBase = blockIdx.x * 2048;
        int total = ET - tileBase; if (total > 2048) total = 2048;
        if (t < NCB) hist[t] = 0;
        __syncthreads();
        unsigned long long ltm = (1ull << lane) - 1ull;

        // Load phase: all 16 ei words issued before the serial ballot chain.
        int sr[8], dr[8];
        #pragma unroll
        for (int r = 0; r < 8; ++r) {
            int i = tileBase + r * 256 + t;
            int s = 0, d = -1;
            if (i < ET) {
                if (i < N_EDGES) { s = ei[i]; d = ei[N_EDGES + i]; }
                else             { s = d = i - N_EDGES; }
            }
            sr[r] = s; dr[r] = d;
        }
        __builtin_amdgcn_sched_barrier(0);   // keep loads above, in flight

        unsigned int pk[8]; int ps[8];
        #pragma unroll
        for (int r = 0; r < 8; ++r) {
            int s = sr[r], d = dr[r];
            int b = (d >= 0) ? (d >> 14) : -1;
            unsigned long long m[NCB];
            #pragma unroll
            for (int q = 0; q < NCB; ++q) m[q] = __ballot(b == q);
            int cnt = 0;
            #pragma unroll
            for (int q = 0; q < NCB; ++q) if (lane == q) cnt = __popcll(m[q]);
            int old = 0;
            if (lane < NCB) old = atomicAdd(&hist[lane], cnt);
            int bsafe = (b >= 0) ? b : 0;
            int basew = __shfl(old, bsafe, 64);
            if (b >= 0) {
                int rank = 0;
                #pragma unroll
                for (int q = 0; q < NCB; ++q)
                    if (b == q) rank = (int)__popcll(m[q] & ltm);
                pk[r] = ((unsigned int)s << 14) | ((unsigned int)d & 16383u);
                ps[r] = (basew + rank) | (b << 12);
            } else ps[r] = -1;
        }
        __syncthreads();
        if (t == 0) {
            int run = 0;
            #pragma unroll
            for (int q = 0; q < NCB; ++q) { int h = hist[q]; lb[q] = run; run += h; }
        }
        __syncthreads();
        if (t < NCB) {
            int g = (hist[t] > 0) ? atomicAdd(&tail1[t], hist[t]) : 0;
            cbase[t] = g - lb[t];
        }
        #pragma unroll
        for (int r = 0; r < 8; ++r) {
            if (ps[r] >= 0) {
                int b = ps[r] >> 12, pos = ps[r] & 4095;
                eb[lb[b] + pos] = pk[r];
            }
        }
        __syncthreads();
        int B1 = lb[1], B2 = lb[2], B3 = lb[3], B4 = lb[4], B5 = lb[5], B6 = lb[6];
        for (int j = t; j < total; j += 256) {
            unsigned int p = eb[j];
            int b = (j >= B1) + (j >= B2) + (j >= B3) + (j >= B4)
                  + (j >= B5) + (j >= B6);
            buf1[(size_t)b * CAP1 + cbase[b] + j] = p;
        }
    } else {
        // -------- fused lin1 + GAT-0 gemm/att (unchanged numerics) --------
        int quad = lane >> 4, lr = lane & 15;
        int rowg0 = (int)(blockIdx.x - NT1) * 64 + w * 16;
        float* xs = (float*)smem + w * (16 * 68);

        // GEMM 1: h0 = relu(x@W1+b1), K=128.
        // All 8 x-loads issued, then fence: 8 outstanding loads per lane.
        int arow = rowg0 + lr; if (arow >= N_NODES) arow = N_NODES - 1;
        const float* ab = x + (size_t)arow * F_IN + quad * 8;
        float4 xa[8];
        #pragma unroll
        for (int kc = 0; kc < 4; ++kc) {
            xa[2 * kc]     = *(const float4*)(ab + kc * 32);
            xa[2 * kc + 1] = *(const float4*)(ab + kc * 32 + 4);
        }
        __builtin_amdgcn_sched_barrier(0);   // forbid sinking the loads

        f32x4 zero = {0.f, 0.f, 0.f, 0.f};
        f32x4 acc[4] = {zero, zero, zero, zero};
        #pragma unroll
        for (int kc = 0; kc < 4; ++kc) {
            bf16x8 bw[4];
            #pragma unroll
            for (int nt = 0; nt < 4; ++nt)
                bw[nt] = *(const bf16x8*)(Wt1 + (nt * 16 + lr) * F_IN
                                          + kc * 32 + quad * 8);
            float4 a0 = xa[2 * kc], a1 = xa[2 * kc + 1];
            union { bf16x8 v; unsigned int u[4]; } af;
            af.u[0] = f2bf(a0.x) | (f2bf(a0.y) << 16);
            af.u[1] = f2bf(a0.z) | (f2bf(a0.w) << 16);
            af.u[2] = f2bf(a1.x) | (f2bf(a1.y) << 16);
            af.u[3] = f2bf(a1.z) | (f2bf(a1.w) << 16);
            #pragma unroll
            for (int nt = 0; nt < 4; ++nt)
                acc[nt] = __builtin_amdgcn_mfma_f32_16x16x32_bf16(
                              af.v, bw[nt], acc[nt], 0, 0, 0);
        }
        #pragma unroll
        for (int nt = 0; nt < 4; ++nt) {
            float bv = b1[nt * 16 + lr];
            #pragma unroll
            for (int reg = 0; reg < 4; ++reg)
                xs[(quad * 4 + reg) * 68 + nt * 16 + lr] =
                    fmaxf(acc[nt][reg] + bv, 0.f);
        }
        // GEMM 2: h = h0@Wc0, K=64, A from LDS (wave-local, no barriers)
        f32x4 acc2[4] = {zero, zero, zero, zero};
        #pragma unroll
        for (int kc = 0; kc < 2; ++kc) {
            bf16x8 bw[4];
            #pragma unroll
            for (int nt = 0; nt < 4; ++nt)
                bw[nt] = *(const bf16x8*)(Wtc0 + (nt * 16 + lr) * HID
                                          + kc * 32 + quad * 8);
            const float* ap = xs + lr * 68 + kc * 32 + quad * 8;
            float4 a0 = *(const float4*)ap;
            float4 a1 = *(const float4*)(ap + 4);
            union { bf16x8 v; unsigned int u[4]; } af;
            af.u[0] = f2bf(a0.x) | (f2bf(a0.y) << 16);
            af.u[1] = f2bf(a0.z) | (f2bf(a0.w) << 16);
            af.u[2] = f2bf(a1.x) | (f2bf(a1.y) << 16);
            af.u[3] = f2bf(a1.z) | (f2bf(a1.w) << 16);
            #pragma unroll
            for (int nt = 0; nt < 4; ++nt)
                acc2[nt] = __builtin_amdgcn_mfma_f32_16x16x32_bf16(
                              af.v, bw[nt], acc2[nt], 0, 0, 0);
        }
        float asv[4], adv[4];
        #pragma unroll
        for (int nt = 0; nt < 4; ++nt) {
            asv[nt] = att_s[nt * 16 + lr];
            adv[nt] = att_d[nt * 16 + lr];
        }
        #pragma unroll
        for (int reg = 0; reg < 4; ++reg) {
            float p1 = acc2[0][reg] * asv[0] + acc2[1][reg] * asv[1]
                     + acc2[2][reg] * asv[2] + acc2[3][reg] * asv[3];
            float p2 = acc2[0][reg] * adv[0] + acc2[1][reg] * adv[1]
                     + acc2[2][reg] * adv[2] + acc2[3][reg] * adv[3];
            #pragma unroll
            for (int off = 1; off < 16; off <<= 1) {
                p1 += __shfl_xor(p1, off, 64);
                p2 += __shfl_xor(p2, off, 64);
            }
            if (lr == 0) {
                int grow = rowg0 + quad * 4 + reg;
                if (grow < N_NODES) { as_[grow] = p1; ad_[grow] = p2; }
            }
        }
        #pragma unroll
        for (int nt = 0; nt < 4; ++nt)
            #pragma unroll
            for (int reg = 0; reg < 4; ++reg)
                xs[(quad * 4 + reg) * 68 + nt * 16 + lr] = acc2[nt][reg];
        #pragma unroll
        for (int j = 0; j < 2; ++j) {
            int task = j * 64 + lane;
            int r = task >> 3, g = task & 7;
            int grow = rowg0 + r;
            if (grow < N_NODES) {
                const float* p = xs + r * 68 + g * 8;
                uint4 u;
                u.x = f2bf(p[0]) | (f2bf(p[1]) << 16);
                u.y = f2bf(p[2]) | (f2bf(p[3]) << 16);
                u.z = f2bf(p[4]) | (f2bf(p[5]) << 16);
                u.w = f2bf(p[6]) | (f2bf(p[7]) << 16);
                *(uint4*)(hb + (size_t)grow * HID + g * 8) = u;
            }
        }
    }
}

// ---------------------------------------------------------------------------
// Partition level 2: coarse bucket -> 128 fine buckets. Packed uint payload.
// Last finishing block performs the fine-bucket exclusive scan.
// ---------------------------------------------------------------------------
__global__ __launch_bounds__(256) void k_part2(const unsigned int* __restrict__ buf1,
        const int* __restrict__ tail1, int* __restrict__ fcnt,
        unsigned int* __restrict__ buf2, int* __restrict__ fbase,
        int* __restrict__ rowptr, int* __restrict__ done0) {
    __shared__ unsigned int eb[2048];
    __shared__ int hist[128], lbase[128], loff[128], goff[128], sc[128];
    __shared__ int lastflag, wsum4[4];
    int t = threadIdx.x;
    int cb   = blockIdx.x / BPC;
    int tile = blockIdx.x % BPC;
    int n1 = tail1[cb];
    int base = tile * 2048;
    if (base < n1) {
        int total = n1 - base; if (total > 2048) total = 2048;
        if (t < 128) hist[t] = 0;
        __syncthreads();
        unsigned int pr[8]; int fr[8];
        #pragma unroll
        for (int r = 0; r < 8; ++r) {
            int i = base + r * 256 + t;
            int f = -1; unsigned int p = 0;
            if (i < n1) {
                p = buf1[(size_t)cb * CAP1 + i];
                f = (int)((p >> 7) & 127u);
                atomicAdd(&hist[f], 1);
            }
            pr[r] = p; fr[r] = f;
        }
        __syncthreads();
        if (t < 128) sc[t] = hist[t];
        __syncthreads();
        for (int off = 1; off < 128; off <<= 1) {
            int u = (t < 128 && t >= off) ? sc[t - off] : 0;
            __syncthreads();
            if (t < 128) sc[t] += u;
            __syncthreads();
        }
        if (t < 128) { lbase[t] = sc[t] - hist[t]; loff[t] = 0; }
        __syncthreads();
        if (t < 128 && hist[t] > 0)
            goff[t] = atomicAdd(&fcnt[cb * 128 + t], hist[t]);
        #pragma unroll
        for (int r = 0; r < 8; ++r) {
            if (fr[r] >= 0) {
                int f = fr[r];
                int pos = lbase[f] + atomicAdd(&loff[f], 1);
                eb[pos] = (pr[r] & 127u) | ((pr[r] >> 14) << 7)
                        | ((unsigned int)f << 24);
            }
        }
        __syncthreads();
        for (int j = t; j < total; j += 256) {
            unsigned int q = eb[j];
            int f = (int)(q >> 24);
            buf2[(size_t)(cb * 128 + f) * CAPF + goff[f] + (j - lbase[f])] =
                q & 0xFFFFFFu;
        }
    }
    // ---- done-ticket: last block of the grid runs the fine scan ----
    if (t == 0) lastflag = (atomicAdd(done0, 1) == NCB * BPC - 1);
    __syncthreads();
    if (lastflag) {
        __threadfence();
        int k0 = t * 4;
        int v0 = (k0     < NFB) ? fcnt[k0]     : 0;
        int v1 = (k0 + 1 < NFB) ? fcnt[k0 + 1] : 0;
        int v2 = (k0 + 2 < NFB) ? fcnt[k0 + 2] : 0;
        int v3 = (k0 + 3 < NFB) ? fcnt[k0 + 3] : 0;
        int s1 = v0 + v1, s2 = s1 + v2, s3 = s2 + v3;
        int lane = t & 63, w = t >> 6;
        int ws = s3;
        #pragma unroll
        for (int off = 1; off < 64; off <<= 1) {
            int u = __shfl_up(ws, off, 64);
            if (lane >= off) ws += u;
        }
        if (lane == 63) wsum4[w] = ws;
        __syncthreads();
        int wb = 0;
        #pragma unroll
        for (int q = 0; q < 4; ++q) if (q < w) wb += wsum4[q];
        int ex = wb + ws - s3;
        if (k0     < NFB) fbase[k0]     = ex;
        if (k0 + 1 < NFB) fbase[k0 + 1] = ex + v0;
        if (k0 + 2 < NFB) fbase[k0 + 2] = ex + s1;
        if (k0 + 3 < NFB) fbase[k0 + 3] = ex + s2;
        if (t == 0) rowptr[N_NODES] = ET;
    }
}

// ---------------------------------------------------------------------------
// Partition level 3: fine bucket -> exact per-node CSR + degree histogram.
// Last finishing block performs the 64-entry degree scan.
// ---------------------------------------------------------------------------
__global__ __launch_bounds__(256) void k_part3(const unsigned int* __restrict__ buf2,
        const int* __restrict__ fcnt, const int* __restrict__ fbase,
        int* __restrict__ rowptr, int* __restrict__ col,
        int* __restrict__ dhistg, int* __restrict__ dbase,
        int* __restrict__ done1) {
    __shared__ unsigned int eb[CAPF];
    __shared__ int cs[CAPF];
    __shared__ int hist[128], lbase[128], loff[128], sc[128], dh[64];
    __shared__ int lastflag;
    int t = threadIdx.x;
    int fb = blockIdx.x;
    int nF = fcnt[fb];
    int gb = fbase[fb];
    int nbase = fb * 128;
    if (t < 128) hist[t] = 0;
    if (t >= 128 && t < 192) dh[t - 128] = 0;
    __syncthreads();
    for (int j = t; j < nF; j += 256) {
        unsigned int q = buf2[(size_t)fb * CAPF + j];
        eb[j] = q;
        atomicAdd(&hist[q & 127u], 1);
    }
    __syncthreads();
    if (t < 128) sc[t] = hist[t];
    __syncthreads();
    for (int off = 1; off < 128; off <<= 1) {
        int u = (t < 128 && t >= off) ? sc[t - off] : 0;
        __syncthreads();
        if (t < 128) sc[t] += u;
        __syncthreads();
    }
    if (t < 128) { lbase[t] = sc[t] - hist[t]; loff[t] = 0; }
    __syncthreads();
    if (t < 128 && nbase + t < N_NODES) {
        rowptr[nbase + t] = gb + lbase[t];
        int dg = hist[t]; if (dg > 63) dg = 63;
        atomicAdd(&dh[dg], 1);
    }
    for (int j = t; j < nF; j += 256) {
        unsigned int q = eb[j];
        int r = (int)(q & 127u);
        int p = lbase[r] + atomicAdd(&loff[r], 1);
        cs[p] = (int)(q >> 7);
    }
    __syncthreads();
    for (int j = t; j < nF; j += 256) col[gb + j] = cs[j];
    if (t < 64 && dh[t] > 0) atomicAdd(&dhistg[t], dh[t]);
    __syncthreads();
    // ---- done-ticket: last block runs the degree scan ----
    if (t == 0) lastflag = (atomicAdd(done1, 1) == NFB - 1);
    __syncthreads();
    if (lastflag && t < 64) {
        __threadfence();
        int v = dhistg[t];
        int s = v;
        #pragma unroll
        for (int off = 1; off < 64; off <<= 1) {
            int u = __shfl_up(s, off, 64);
            if (t >= off) s += u;
        }
        dbase[t] = s - v;   // exclusive
    }
}

// ---------------------------------------------------------------------------
__global__ __launch_bounds__(256) void k_dscatter(const int* __restrict__ rowptr,
        int* __restrict__ dbase, int* __restrict__ nodeord) {
    __shared__ int lh[64], goff[64];
    int t = threadIdx.x;
    if (t < 64) lh[t] = 0;
    __syncthreads();
    int i = blockIdx.x * 256 + t;
    int deg = -1, lrank = 0;
    if (i < N_NODES) {
        deg = rowptr[i + 1] - rowptr[i];
        if (deg > 63) deg = 63;
        lrank = atomicAdd(&lh[deg], 1);
    }
    __syncthreads();
    if (t < 64) goff[t] = (lh[t] > 0) ? atomicAdd(&dbase[t], lh[t]) : 0;
    __syncthreads();
    if (deg >= 0) nodeord[goff[deg] + lrank] = i;
}

// ---------------------------------------------------------------------------
// h = hin @ Wc (MFMA, bf16 in/out) ; as_/ad_ att dots. (layer 1)
// ---------------------------------------------------------------------------
__global__ __launch_bounds__(256) void k_gemm_att(
        const unsigned short* __restrict__ hin,
        const unsigned short* __restrict__ Wt,
        const float* __restrict__ att_s, const float* __restrict__ att_d,
        unsigned short* __restrict__ hb, float* __restrict__ as_,
        float* __restrict__ ad_) {
    __shared__ float xs[4][16 * 68];
    int t = threadIdx.x;
    int lane = t & 63, w = t >> 6;
    int quad = lane >> 4, lr = lane & 15;
    int rowg0 = blockIdx.x * 64 + w * 16;

    bf16x8 bfr[2][4];
    #pragma unroll
    for (int kc = 0; kc < 2; ++kc)
        #pragma unroll
        for (int nt = 0; nt < 4; ++nt)
            bfr[kc][nt] = *(const bf16x8*)(Wt + (nt * 16 + lr) * HID
                                           + kc * 32 + quad * 8);
    f32x4 zero = {0.f, 0.f, 0.f, 0.f};
    f32x4 acc[4] = {zero, zero, zero, zero};

    int arow = rowg0 + lr; if (arow >= N_NODES) arow = N_NODES - 1;
    #pragma unroll
    for (int kc = 0; kc < 2; ++kc) {
        bf16x8 af = *(const bf16x8*)(hin + (size_t)arow * HID
                                     + kc * 32 + quad * 8);
        #pragma unroll
        for (int nt = 0; nt < 4; ++nt)
            acc[nt] = __builtin_amdgcn_mfma_f32_16x16x32_bf16(
                          af, bfr[kc][nt], acc[nt], 0, 0, 0);
    }
    float asv[4], adv[4];
    #pragma unroll
    for (int nt = 0; nt < 4; ++nt) {
        asv[nt] = att_s[nt * 16 + lr];
        adv[nt] = att_d[nt * 16 + lr];
    }
    #pragma unroll
    for (int reg = 0; reg < 4; ++reg) {
        float p1 = acc[0][reg] * asv[0] + acc[1][reg] * asv[1]
                 + acc[2][reg] * asv[2] + acc[3][reg] * asv[3];
        float p2 = acc[0][reg] * adv[0] + acc[1][reg] * adv[1]
                 + acc[2][reg] * adv[2] + acc[3][reg] * adv[3];
        #pragma unroll
        for (int off = 1; off < 16; off <<= 1) {
            p1 += __shfl_xor(p1, off, 64);
            p2 += __shfl_xor(p2, off, 64);
        }
        if (lr == 0) {
            int grow = rowg0 + quad * 4 + reg;
            if (grow < N_NODES) { as_[grow] = p1; ad_[grow] = p2; }
        }
    }
    #pragma unroll
    for (int nt = 0; nt < 4; ++nt)
        #pragma unroll
        for (int reg = 0; reg < 4; ++reg)
            xs[w][(quad * 4 + reg) * 68 + nt * 16 + lr] = acc[nt][reg];
    #pragma unroll
    for (int j = 0; j < 2; ++j) {
        int task = j * 64 + lane;
        int r = task >> 3, g = task & 7;
        int grow = rowg0 + r;
        if (grow < N_NODES) {
            const float* p = xs[w] + r * 68 + g * 8;
            uint4 u;
            u.x = f2bf(p[0]) | (f2bf(p[1]) << 16);
            u.y = f2bf(p[2]) | (f2bf(p[3]) << 16);
            u.z = f2bf(p[4]) | (f2bf(p[5]) << 16);
            u.w = f2bf(p[6]) | (f2bf(p[7]) << 16);
            *(uint4*)(hb + (size_t)grow * HID + g * 8) = u;
        }
    }
}

// ---------------------------------------------------------------------------
// Fused GAT aggregate: 8 lanes per dst, 8 dsts per wave (degree-sorted).
// Gather batch fenced from FMA batch; next chunk's col/as_/expf prelude
// issued before the FMAs so its latency hides under them.
// ---------------------------------------------------------------------------
template <bool RELU>
__global__ __launch_bounds__(256) void k_gat_agg(const int* __restrict__ rowptr,
        const int* __restrict__ col, const unsigned short* __restrict__ hb,
        const float* __restrict__ as_, const float* __restrict__ ad_,
        const float* __restrict__ bias, const int* __restrict__ nodeord,
        unsigned short* __restrict__ outb) {
    int t = threadIdx.x;
    int lane = t & 63;
    int wid = blockIdx.x * 4 + (t >> 6);
    int l8 = lane & 7;
    int ch = l8 * 8;
    int d = nodeord[wid * 8 + (lane >> 3)];
    int beg = rowptr[d];
    int deg = rowptr[d + 1] - beg;
    float add = ad_[d];
    int degw = deg;
    degw = max(degw, __shfl_xor(degw, 8, 64));
    degw = max(degw, __shfl_xor(degw, 16, 64));
    degw = max(degw, __shfl_xor(degw, 32, 64));

    float a0=0.f,a1=0.f,a2=0.f,a3=0.f,a4=0.f,a5=0.f,a6=0.f,a7=0.f,den=0.f;
    const unsigned short* hch = hb + ch;

    // prelude for chunk 0
    int sj = 0; float wj = 0.f;
    if (l8 < deg) {
        sj = col[beg + l8];
        float e = as_[sj] + add;
        e = (e > 0.f) ? e : NEG_SLOPE * e;
        wj = __expf(e);
    }
    for (int c = 0; c < degw; c += 8) {
        uint4 hv[8]; float w0[8];
        #pragma unroll
        for (int j = 0; j < 8; ++j) {
            int sl = (lane & 56) | j;
            int s = __shfl(sj, sl, 64);
            w0[j] = __shfl(wj, sl, 64);      // 0 for padded slots
            hv[j] = *(const uint4*)(hch + (size_t)s * HID);
        }
        // prelude for next chunk (latency hides under this chunk's FMAs)
        int sjn = 0; float wjn = 0.f;
        int idxn = c + 8 + l8;
        if (c + 8 < degw && idxn < deg) {
            sjn = col[beg + idxn];
            float e = as_[sjn] + add;
            e = (e > 0.f) ? e : NEG_SLOPE * e;
            wjn = __expf(e);
        }
        __builtin_amdgcn_sched_barrier(0);   // keep gathers + prelude above
        #pragma unroll
        for (int j = 0; j < 8; ++j) {
            den += w0[j];
            a0 = fmaf(w0[j], __uint_as_float(hv[j].x << 16),         a0);
            a1 = fmaf(w0[j], __uint_as_float(hv[j].x & 0xffff0000u), a1);
            a2 = fmaf(w0[j], __uint_as_float(hv[j].y << 16),         a2);
            a3 = fmaf(w0[j], __uint_as_float(hv[j].y & 0xffff0000u), a3);
            a4 = fmaf(w0[j], __uint_as_float(hv[j].z << 16),         a4);
            a5 = fmaf(w0[j], __uint_as_float(hv[j].z & 0xffff0000u), a5);
            a6 = fmaf(w0[j], __uint_as_float(hv[j].w << 16),         a6);
            a7 = fmaf(w0[j], __uint_as_float(hv[j].w & 0xffff0000u), a7);
        }
        sj = sjn; wj = wjn;
    }
    float inv = 1.f / (den + 1e-16f);
    float4 bA = *(const float4*)(bias + ch);
    float4 bB = *(const float4*)(bias + ch + 4);
    float o0 = fmaf(a0, inv, bA.x), o1 = fmaf(a1, inv, bA.y);
    float o2 = fmaf(a2, inv, bA.z), o3 = fmaf(a3, inv, bA.w);
    float o4 = fmaf(a4, inv, bB.x), o5 = fmaf(a5, inv, bB.y);
    float o6 = fmaf(a6, inv, bB.z), o7 = fmaf(a7, inv, bB.w);
    if (RELU) {
        o0 = fmaxf(o0, 0.f); o1 = fmaxf(o1, 0.f);
        o2 = fmaxf(o2, 0.f); o3 = fmaxf(o3, 0.f);
        o4 = fmaxf(o4, 0.f); o5 = fmaxf(o5, 0.f);
        o6 = fmaxf(o6, 0.f); o7 = fmaxf(o7, 0.f);
    }
    uint4 u;
    u.x = f2bf(o0) | (f2bf(o1) << 16);
    u.y = f2bf(o2) | (f2bf(o3) << 16);
    u.z = f2bf(o4) | (f2bf(o5) << 16);
    u.w = f2bf(o6) | (f2bf(o7) << 16);
    *(uint4*)(outb + (size_t)d * HID + ch) = u;
}

// ---------------------------------------------------------------------------
// logits = aggb @ W2 + b2 (MFMA bf16, N padded to 48) ; out = log_softmax.
// ---------------------------------------------------------------------------
__global__ __launch_bounds__(256) void k_final(
        const unsigned short* __restrict__ aggb,
        const unsigned short* __restrict__ W2t, const float* __restrict__ b2,
        float* __restrict__ out) {
    __shared__ float xs[64 * 44];
    int t = threadIdx.x;
    int lane = t & 63, w = t >> 6;
    int quad = lane >> 4, lr = lane & 15;
    int rowg0 = blockIdx.x * 64 + w * 16;
    int base = blockIdx.x * 64;
    int rem = N_NODES - base; if (rem > 64) rem = 64;

    bf16x8 bfr[2][3];
    #pragma unroll
    for (int kc = 0; kc < 2; ++kc)
        #pragma unroll
        for (int nt = 0; nt < 3; ++nt)
            bfr[kc][nt] = *(const bf16x8*)(W2t + (nt * 16 + lr) * HID
                                           + kc * 32 + quad * 8);
    f32x4 zero = {0.f, 0.f, 0.f, 0.f};
    f32x4 acc[3] = {zero, zero, zero};
    int arow = rowg0 + lr; if (arow >= N_NODES) arow = N_NODES - 1;
    #pragma unroll
    for (int kc = 0; kc < 2; ++kc) {
        bf16x8 af = *(const bf16x8*)(aggb + (size_t)arow * HID
                                     + kc * 32 + quad * 8);
        #pragma unroll
        for (int nt = 0; nt < 3; ++nt)
            acc[nt] = __builtin_amdgcn_mfma_f32_16x16x32_bf16(
                          af, bfr[kc][nt], acc[nt], 0, 0, 0);
    }
    float bc[3];
    #pragma unroll
    for (int nt = 0; nt < 3; ++nt) {
        int cl = nt * 16 + lr;
        bc[nt] = (cl < N_CLASS) ? b2[cl] : -1e30f;
    }
    #pragma unroll
    for (int reg = 0; reg < 4; ++reg) {
        float v0 = acc[0][reg] + bc[0];
        float v1 = acc[1][reg] + bc[1];
        float v2 = acc[2][reg] + bc[2];
        float m = fmaxf(fmaxf(v0, v1), v2);
        #pragma unroll
        for (int off = 1; off < 16; off <<= 1)
            m = fmaxf(m, __shfl_xor(m, off, 64));
        float ss = __expf(v0 - m) + __expf(v1 - m) + __expf(v2 - m);
        #pragma unroll
        for (int off = 1; off < 16; off <<= 1)
            ss += __shfl_xor(ss, off, 64);
        float lse = m + logf(ss);
        int r = w * 16 + quad * 4 + reg;
        xs[r * 44 + lr]      = v0 - lse;
        xs[r * 44 + 16 + lr] = v1 - lse;
        if (lr < 8) xs[r * 44 + 32 + lr] = v2 - lse;
    }
    __syncthreads();
    #pragma unroll
    for (int j = 0; j < 3; ++j) {
        int idx = j * 256 + t;             // float4 index, 10 per row
        if (idx < rem * 10) {
            int r = idx / 10, c4 = idx - r * 10;
            float4 v = *(const float4*)(xs + r * 44 + c4 * 4);
            *(float4*)(out + (size_t)base * N_CLASS + idx * 4) = v;
        }
    }
}

// ---------------------------------------------------------------------------
extern "C" void kernel_launch(void* const* d_in, const int* in_sizes, int n_in,
                              void* d_out, int out_size, void* d_ws, size_t ws_size,
                              hipStream_t stream) {
    const float* x     = (const float*)d_in[0];
    const int*   ei    = (const int*)  d_in[1];
    const float* W1    = (const float*)d_in[2];
    const float* b1    = (const float*)d_in[3];
    const float* Wc0   = (const float*)d_in[4];
    const float* as0   = (const float*)d_in[5];
    const float* ad0   = (const float*)d_in[6];
    const float* bias0 = (const float*)d_in[7];
    const float* Wc1   = (const float*)d_in[8];
    const float* as1   = (const float*)d_in[9];
    const float* ad1   = (const float*)d_in[10];
    const float* bias1 = (const float*)d_in[11];
    const float* W2    = (const float*)d_in[12];
    const float* b2    = (const float*)d_in[13];
    float* out = (float*)d_out;

    // ---- workspace layout (~50 MB) ----
    char* p = (char*)d_ws;
    unsigned short* hb    = (unsigned short*)p; p += (size_t)N_NODES * HID * 2;
    unsigned short* agg0b = (unsigned short*)p; p += (size_t)N_NODES * HID * 2;
    char* pbuf = p;
    unsigned int*   buf1  = (unsigned int*)pbuf;
    unsigned int*   buf2  = (unsigned int*)(pbuf + (size_t)NCB * CAP1 * 4);
    unsigned short* agg1b = (unsigned short*)pbuf;     // 12.8MB <= 16.47MB
    p += (size_t)NCB * CAP1 * 4 + (size_t)NFB * CAPF * 4;
    int* col = (int*)p;                          p += (size_t)ET * 4;
    unsigned short* Wt1  = (unsigned short*)p;   p += F_IN * HID * 2;
    unsigned short* Wtc0 = (unsigned short*)p;   p += HID * HID * 2;
    unsigned short* Wtc1 = (unsigned short*)p;   p += HID * HID * 2;
    unsigned short* W2t  = (unsigned short*)p;   p += 48 * HID * 2;
    float* as_ = (float*)p;                      p += (size_t)N_NODES * 4;
    float* ad_ = (float*)p;                      p += (size_t)N_NODES * 4;
    int* tail1 = (int*)p;
    int* fcnt  = tail1 + NCB;
    int* fbase = fcnt + NFB;
    int* dhist = fbase + NFB;
    int* dbase = dhist + 64;
    int* done  = dbase + 64;                     // done[0]=part2, done[1]=part3
    const int ZCOUNT = NCB + 2 * NFB + 128 + 2;  // 1701
    p += (size_t)ZCOUNT * 4;
    int* rowptr  = (int*)p;                      p += (size_t)(N_NODES + 1) * 4;
    int* nodeord = (int*)p;

    const int AGG_BLOCKS  = N_NODES / 32;        // 3125: 4 waves x 8 dsts
    const int NODE_BLOCKS = (N_NODES + 255) / 256;

    k_prepw<<<32, 256, 0, stream>>>(W1, Wc0, Wc1, W2, Wt1, Wtc0, Wtc1, W2t,
                                    tail1, ZCOUNT);
    k_p1lin<<<NT1 + ROW_BLOCKS, 256, 0, stream>>>(
        ei, tail1, buf1, x, Wt1, b1, Wtc0, as0, ad0, hb, as_, ad_);
    k_part2<<<NCB * BPC, 256, 0, stream>>>(buf1, tail1, fcnt, buf2, fbase,
                                           rowptr, done + 0);
    k_part3<<<NFB, 256, 0, stream>>>(buf2, fcnt, fbase, rowptr, col, dhist,
                                     dbase, done + 1);
    k_dscatter<<<NODE_BLOCKS, 256, 0, stream>>>(rowptr, dbase, nodeord);

    k_gat_agg<true><<<AGG_BLOCKS, 256, 0, stream>>>(
        rowptr, col, hb, as_, ad_, bias0, nodeord, agg0b);

    k_gemm_att<<<ROW_BLOCKS, 256, 0, stream>>>(agg0b, Wtc1, as1, ad1,
                                               hb, as_, ad_);
    k_gat_agg<false><<<AGG_BLOCKS, 256, 0, stream>>>(
        rowptr, col, hb, as_, ad_, bias1, nodeord, agg1b);

    k_final<<<ROW_BLOCKS, 256, 0, stream>>>(agg1b, W2t, b2, out);
}